// Round 10
// baseline (160.781 us; speedup 1.0000x reference)
//
#include <hip/hip_runtime.h>
#include <math.h>

// NoisyTopKRouter, round 10: 1-pass f16-hi MFMA + certified top-3 gaps +
// exact f32 fixup for ambiguous tokens.
// Main kernel: TOKB=16, grid 1024 x 512 thr (4 blocks/CU -> 32 waves/CU),
// wave = 16 tok x 64 cols x 512-K slice, no LDS/barriers in main loop.
// Certificate: sigma0 = 4.0e-4 per logit; flag if top-3 gaps < 5.5-sigma
// pair bounds (using per-candidate eps and per-token max |eps|).

typedef _Float16 f16;
typedef _Float16 f16x8 __attribute__((ext_vector_type(8)));
typedef float    f32x4 __attribute__((ext_vector_type(4)));

#define NEMBD 2048
#define NEXP  64
#define TOKB  16
#define PSTR  20
#define WSCALE 64.0f
#define INV_WSCALE 0.015625f
#define TAU_C 2.2e-3f

union F4H8 { float4 f; f16x8 h; };

__device__ __forceinline__ f16x8 ld16h(const f16* p) {
    F4H8 u; u.f = *(const float4*)p; return u.h;
}

// ---------- kernel 0: W -> transposed, x64-scaled f16 limbs ----------
// wt layout per limb: [chunk 64][n 128][k 32] f16 (n: 0..63 route, 64..127 noise)
__global__ __launch_bounds__(256) void build_wt(
    const float* __restrict__ Wr, const float* __restrict__ Wn,
    f16* __restrict__ wt_hi, f16* __restrict__ wt_lo)
{
    __shared__ float ws[32][129];
    const int c = blockIdx.x, t = threadIdx.x;
    const int k0 = c * 32;
    {
        const int k  = t >> 3;
        const int n8 = (t & 7) << 3;
        const float* s0 = Wr + (size_t)(k0 + k) * NEXP + n8;
        const float* s1 = Wn + (size_t)(k0 + k) * NEXP + n8;
        #pragma unroll
        for (int j = 0; j < 8; ++j) ws[k][n8 + j] = s0[j];
        #pragma unroll
        for (int j = 0; j < 8; ++j) ws[k][64 + n8 + j] = s1[j];
    }
    __syncthreads();
    {
        const int n  = t >> 1;           // 0..127
        const int kh = (t & 1) << 4;     // 0 or 16
        f16x8 hv0, hv1, lv0, lv1;
        #pragma unroll
        for (int j = 0; j < 8; ++j) {
            const float v = ws[kh + j][n] * WSCALE;
            const f16 h = (f16)v;
            hv0[j] = h; lv0[j] = (f16)(v - (float)h);
        }
        #pragma unroll
        for (int j = 0; j < 8; ++j) {
            const float v = ws[kh + 8 + j][n] * WSCALE;
            const f16 h = (f16)v;
            hv1[j] = h; lv1[j] = (f16)(v - (float)h);
        }
        const size_t base = ((size_t)c * 128 + n) * 32 + kh;
        *(f16x8*)(wt_hi + base)     = hv0;
        *(f16x8*)(wt_hi + base + 8) = hv1;
        *(f16x8*)(wt_lo + base)     = lv0;
        *(f16x8*)(wt_lo + base + 8) = lv1;
    }
}

// ---------- kernel 1: 1-pass router + gap certification ----------
// 512 thr = 8 waves = 2 col-halves x 4 K-quarters. Wave (ch,kq):
// 16 tokens x cols [ch*64, +64) x K [kq*512, +512).
__global__ __launch_bounds__(512, 8) void router_fused8(
    const float* __restrict__ x, const float* __restrict__ eps,
    const f16* __restrict__ wt_hi,
    const float* __restrict__ br, const float* __restrict__ bn,
    float* __restrict__ out_r, float* __restrict__ out_idx,
    int* __restrict__ cnt, int* __restrict__ list)
{
    __shared__ __align__(16) float P[2][128 * PSTR];   // 20,480 B
    __shared__ float TK[4 * TOKB];

    const int tid  = threadIdx.x;
    const int lane = tid & 63;
    const int w    = tid >> 6;
    const int ch   = w & 1;              // col half
    const int kq   = w >> 1;             // K quarter (0..3)
    const int m0   = blockIdx.x * TOKB;

    const int row16 = lane & 15;
    const int kl    = lane >> 4;         // lane k-group 0..3

    // A: token row m0+row16, K base kq*512 + kl*8
    const float* asrc = x + (size_t)(m0 + row16) * NEMBD + kq * 512 + kl * 8;
    // B: cols ch*64 + f*16 + row16, chunk g = kq*16 + c
    const int bofs = (ch * 64 + row16) * 32 + kl * 8;

    f32x4 acc[4];
    #pragma unroll
    for (int f = 0; f < 4; ++f) acc[f] = (f32x4){0.f, 0.f, 0.f, 0.f};

    #pragma unroll 2
    for (int c = 0; c < 16; ++c) {
        const float4 a0 = *(const float4*)(asrc + c * 32);
        const float4 a1 = *(const float4*)(asrc + c * 32 + 4);
        const size_t cb = (size_t)(kq * 16 + c) * 4096 + bofs;
        const f16x8 b0 = ld16h(wt_hi + cb);
        const f16x8 b1 = ld16h(wt_hi + cb + 512);
        const f16x8 b2 = ld16h(wt_hi + cb + 1024);
        const f16x8 b3 = ld16h(wt_hi + cb + 1536);
        f16x8 ah;
        ah[0] = (f16)a0.x; ah[1] = (f16)a0.y; ah[2] = (f16)a0.z; ah[3] = (f16)a0.w;
        ah[4] = (f16)a1.x; ah[5] = (f16)a1.y; ah[6] = (f16)a1.z; ah[7] = (f16)a1.w;
        acc[0] = __builtin_amdgcn_mfma_f32_16x16x32_f16(ah, b0, acc[0], 0, 0, 0);
        acc[1] = __builtin_amdgcn_mfma_f32_16x16x32_f16(ah, b1, acc[1], 0, 0, 0);
        acc[2] = __builtin_amdgcn_mfma_f32_16x16x32_f16(ah, b2, acc[2], 0, 0, 0);
        acc[3] = __builtin_amdgcn_mfma_f32_16x16x32_f16(ah, b3, acc[3], 0, 0, 0);
    }

    // ---- deterministic split-K reduction ----
    const int tokb = kl << 2;
    if (kq >= 2) {               // write slice kq-2
        float* Ps = P[kq - 2];
        #pragma unroll
        for (int f = 0; f < 4; ++f) {
            const int col = ch * 64 + f * 16 + row16;
            float4 v;
            v.x = acc[f][0] * INV_WSCALE; v.y = acc[f][1] * INV_WSCALE;
            v.z = acc[f][2] * INV_WSCALE; v.w = acc[f][3] * INV_WSCALE;
            *(float4*)(Ps + col * PSTR + tokb) = v;
        }
    }
    __syncthreads();
    if (kq < 2) {                // add into slice kq
        float* Ps = P[kq];
        #pragma unroll
        for (int f = 0; f < 4; ++f) {
            const int col = ch * 64 + f * 16 + row16;
            float* dst = Ps + col * PSTR + tokb;
            float4 d = *(float4*)dst;
            d.x += acc[f][0] * INV_WSCALE; d.y += acc[f][1] * INV_WSCALE;
            d.z += acc[f][2] * INV_WSCALE; d.w += acc[f][3] * INV_WSCALE;
            *(float4*)dst = d;
        }
    }
    __syncthreads();
    {   // fold slice1 -> slice0: 128 cols x 16 tok, one float4 per thread
        const int col = tid >> 2;
        const int tk  = (tid & 3) << 2;
        float* dst = P[0] + col * PSTR + tk;
        const float4 sv = *(const float4*)(P[1] + col * PSTR + tk);
        float4 d = *(float4*)dst;
        d.x += sv.x; d.y += sv.y; d.z += sv.z; d.w += sv.w;
        *(float4*)dst = d;
    }
    __syncthreads();

    // ---- bias + noise + top-3 + certification: 4 lanes per token ----
    if (tid < 64) {
        const int t = tid >> 2;
        const int q = tid & 3;
        const float* ep = eps + (size_t)(m0 + t) * NEXP;
        float v1 = -1e30f, v2 = -1e30f, v3 = -1e30f;
        int i1 = 0, i2 = 0, i3 = 0;
        float mx = 0.f;
        for (int j = 0; j < 16; ++j) {
            const int e = q * 16 + j;
            const float r  = br[e] + P[0][e * PSTR + t];
            const float nr = bn[e] + P[0][(NEXP + e) * PSTR + t];
            const float sp = fmaxf(nr, 0.f) + log1pf(expf(-fabsf(nr)));
            const float ev = ep[e];
            mx = fmaxf(mx, fabsf(ev));
            const float noisy = fmaf(ev, sp, r);
            if (noisy > v1) { v3 = v2; i3 = i2; v2 = v1; i2 = i1; v1 = noisy; i1 = e; }
            else if (noisy > v2) { v3 = v2; i3 = i2; v2 = noisy; i2 = e; }
            else if (noisy > v3) { v3 = noisy; i3 = e; }
        }
        // merge triples across the 4 lanes (prefer lower-index half on ties)
        #pragma unroll
        for (int s = 0; s < 2; ++s) {
            const int dist = 1 << s;
            const float ov1 = __shfl_xor(v1, dist);
            const float ov2 = __shfl_xor(v2, dist);
            const float ov3 = __shfl_xor(v3, dist);
            const int   oi1 = __shfl_xor(i1, dist);
            const int   oi2 = __shfl_xor(i2, dist);
            const int   oi3 = __shfl_xor(i3, dist);
            mx = fmaxf(mx, __shfl_xor(mx, dist));
            const int h = (q >> s) & 1;  // 1 => I'm the upper-index half
            float a1, a2, a3, bb1, bb2, bb3; int ai1, ai2, ai3, bj1, bj2, bj3;
            if (h) { a1=ov1;a2=ov2;a3=ov3;ai1=oi1;ai2=oi2;ai3=oi3;
                     bb1=v1;bb2=v2;bb3=v3;bj1=i1;bj2=i2;bj3=i3; }
            else   { a1=v1;a2=v2;a3=v3;ai1=i1;ai2=i2;ai3=i3;
                     bb1=ov1;bb2=ov2;bb3=ov3;bj1=oi1;bj2=oi2;bj3=oi3; }
            // insert b1,b2,b3 (strict >, preserves lower-index preference)
            #pragma unroll
            for (int bi = 0; bi < 3; ++bi) {
                const float bv = (bi == 0) ? bb1 : (bi == 1) ? bb2 : bb3;
                const int   bj = (bi == 0) ? bj1 : (bi == 1) ? bj2 : bj3;
                if (bv > a1) { a3=a2;ai3=ai2; a2=a1;ai2=ai1; a1=bv;ai1=bj; }
                else if (bv > a2) { a3=a2;ai3=ai2; a2=bv;ai2=bj; }
                else if (bv > a3) { a3=bv;ai3=bj; }
            }
            v1=a1;v2=a2;v3=a3;i1=ai1;i2=ai2;i3=ai3;
        }
        if (q == 0) {
            // certification
            const float e1 = fabsf(ep[i1]);
            const float e2 = fabsf(ep[i2]);
            const float em = fmaxf(e1, e2);
            const float t12 = TAU_C * sqrtf(2.f + e1 * e1 + e2 * e2);
            const float t23 = TAU_C * sqrtf(2.f + em * em + mx * mx);
            if ((v1 - v2 < t12) || (v2 - v3 < t23)) {
                const int ai = atomicAdd(cnt, 1);
                list[ai] = m0 + t;
            }
            const float ex = expf(v2 - v1);
            const float p1 = 1.f / (1.f + ex);
            TK[0 * TOKB + t] = p1;
            TK[1 * TOKB + t] = ex * p1;
            TK[2 * TOKB + t] = (float)i1;
            TK[3 * TOKB + t] = (float)i2;
        }
    }
    __syncthreads();

    // ---- write r_out (float2/thread) + idx ----
    {
        const int t  = tid >> 5;             // 0..15
        const int c2 = (tid & 31) << 1;      // 0..62
        const float p1 = TK[t], p2 = TK[TOKB + t];
        const int i1 = (int)TK[2 * TOKB + t], i2 = (int)TK[3 * TOKB + t];
        float2 v;
        v.x = (c2 == i1) ? p1 : (c2 == i2) ? p2 : 0.f;
        v.y = (c2 + 1 == i1) ? p1 : (c2 + 1 == i2) ? p2 : 0.f;
        *(float2*)(out_r + (size_t)(m0 + t) * NEXP + c2) = v;
    }
    if (tid < TOKB) {
        float2 v = make_float2(TK[2 * TOKB + tid], TK[3 * TOKB + tid]);
        *(float2*)(out_idx + (size_t)(m0 + tid) * 2) = v;
    }
}

// ---------- kernel 2: exact f32 fixup for flagged tokens ----------
// One 128-thread block per flagged token (looped). Reconstructs w from
// hi+lo limbs (sigma ~1.4e-7), exact f32 epilogue, overwrites outputs.
__global__ __launch_bounds__(128) void router_fixup(
    const float* __restrict__ x, const float* __restrict__ eps,
    const f16* __restrict__ wt_hi, const f16* __restrict__ wt_lo,
    const float* __restrict__ br, const float* __restrict__ bn,
    float* __restrict__ out_r, float* __restrict__ out_idx,
    const int* __restrict__ cnt, const int* __restrict__ list)
{
    __shared__ __align__(16) float xs[NEMBD];
    __shared__ float lg[128];
    __shared__ float tk[4];

    const int tid = threadIdx.x;
    const int n = cnt[0];
    for (int it = blockIdx.x; it < n; it += gridDim.x) {
        const int tok = list[it];
        // stage x row (coalesced float4)
        {
            const float4* src = (const float4*)(x + (size_t)tok * NEMBD);
            float4* dst = (float4*)xs;
            #pragma unroll
            for (int j = 0; j < 4; ++j)
                dst[tid + j * 128] = src[tid + j * 128];
        }
        __syncthreads();
        // thread = col 0..127: exact dot via hi+lo limb reconstruction
        {
            const int col = tid;
            float a = 0.f;
            for (int g = 0; g < 64; ++g) {
                const size_t base = ((size_t)g * 128 + col) * 32;
                const float* xr = xs + g * 32;
                #pragma unroll
                for (int kk = 0; kk < 4; ++kk) {
                    const f16x8 hv = ld16h(wt_hi + base + kk * 8);
                    const f16x8 lv = ld16h(wt_lo + base + kk * 8);
                    #pragma unroll
                    for (int j = 0; j < 8; ++j) {
                        const float wv = (float)hv[j] + (float)lv[j];
                        a = fmaf(xr[kk * 8 + j], wv, a);
                    }
                }
            }
            const float bias = (col < NEXP) ? br[col] : bn[col - NEXP];
            lg[col] = a * INV_WSCALE + bias;
        }
        __syncthreads();
        if (tid == 0) {
            const float* ep = eps + (size_t)tok * NEXP;
            float v1 = -1e30f, v2 = -1e30f;
            int i1 = 0, i2 = 0;
            for (int e = 0; e < NEXP; ++e) {
                const float r  = lg[e];
                const float nr = lg[NEXP + e];
                const float sp = fmaxf(nr, 0.f) + log1pf(expf(-fabsf(nr)));
                const float noisy = fmaf(ep[e], sp, r);
                if (noisy > v1) { v2 = v1; i2 = i1; v1 = noisy; i1 = e; }
                else if (noisy > v2) { v2 = noisy; i2 = e; }
            }
            const float ex = expf(v2 - v1);
            const float p1 = 1.f / (1.f + ex);
            tk[0] = p1; tk[1] = ex * p1;
            tk[2] = (float)i1; tk[3] = (float)i2;
        }
        __syncthreads();
        if (tid < NEXP) {
            const int i1 = (int)tk[2], i2 = (int)tk[3];
            out_r[(size_t)tok * NEXP + tid] =
                (tid == i1) ? tk[0] : (tid == i2) ? tk[1] : 0.f;
        }
        if (tid == 0) {
            *(float2*)(out_idx + (size_t)tok * 2) = make_float2(tk[2], tk[3]);
        }
        __syncthreads();
    }
}

// ---------- fallback: fused f32 kernel (insurance only) ----------
__global__ __launch_bounds__(256) void router_fused_f32(
    const float* __restrict__ x, const float* __restrict__ eps,
    const float* __restrict__ Wr, const float* __restrict__ br,
    const float* __restrict__ Wn, const float* __restrict__ bn,
    float* __restrict__ out_r, float* __restrict__ out_idx)
{
    __shared__ float xsm[32][64];
    __shared__ float ws2[32][128];
    __shared__ float lg[128][64];
    __shared__ float tk[4][64];
    const int tid = threadIdx.x;
    const int tx = tid & 15, ty = tid >> 4;
    const int m0 = blockIdx.x * 64;
    float acc[4][8];
    #pragma unroll
    for (int i = 0; i < 4; ++i)
        #pragma unroll
        for (int j = 0; j < 8; ++j) acc[i][j] = 0.f;
    for (int kc = 0; kc < NEMBD; kc += 32) {
        {
            const int tm = tid >> 2, kk = (tid & 3) << 3;
            const float* src = x + (size_t)(m0 + tm) * NEMBD + kc + kk;
            const float4 a = *(const float4*)(src);
            const float4 b = *(const float4*)(src + 4);
            xsm[kk+0][tm]=a.x; xsm[kk+1][tm]=a.y; xsm[kk+2][tm]=a.z; xsm[kk+3][tm]=a.w;
            xsm[kk+4][tm]=b.x; xsm[kk+5][tm]=b.y; xsm[kk+6][tm]=b.z; xsm[kk+7][tm]=b.w;
        }
        {
            const int kr = tid >> 3, q = tid & 7;
            const float* src = (q < 4)
                ? (Wr + (size_t)(kc + kr) * NEXP + (q << 4))
                : (Wn + (size_t)(kc + kr) * NEXP + ((q - 4) << 4));
            float* dst = &ws2[kr][q << 4];
            #pragma unroll
            for (int j = 0; j < 16; ++j) dst[j] = src[j];
        }
        __syncthreads();
        #pragma unroll
        for (int k = 0; k < 32; ++k) {
            const float4 xv = *(const float4*)&xsm[k][ty << 2];
            const float4 wa = *(const float4*)&ws2[k][tx << 3];
            const float4 wb = *(const float4*)&ws2[k][(tx << 3) + 4];
            const float xr[4] = {xv.x, xv.y, xv.z, xv.w};
            const float wcx[8] = {wa.x, wa.y, wa.z, wa.w, wb.x, wb.y, wb.z, wb.w};
            #pragma unroll
            for (int i = 0; i < 4; ++i)
                #pragma unroll
                for (int j = 0; j < 8; ++j)
                    acc[i][j] = fmaf(xr[i], wcx[j], acc[i][j]);
        }
        __syncthreads();
    }
    {
        const int n0 = tx << 3;
        #pragma unroll
        for (int j = 0; j < 8; ++j) {
            const int nn = n0 + j;
            const float b = (nn < NEXP) ? br[nn] : bn[nn - NEXP];
            #pragma unroll
            for (int i = 0; i < 4; ++i)
                lg[nn][(ty << 2) + i] = acc[i][j] + b;
        }
    }
    __syncthreads();
    if (tid < 64) {
        const int t = tid;
        const float* ep = eps + (size_t)(m0 + t) * NEXP;
        float v1 = -1e30f, v2 = -1e30f; int i1 = 0, i2 = 0;
        for (int e = 0; e < NEXP; ++e) {
            const float r = lg[e][t], nr = lg[NEXP + e][t];
            const float sp = fmaxf(nr, 0.f) + log1pf(expf(-fabsf(nr)));
            const float noisy = fmaf(ep[e], sp, r);
            if (noisy > v1) { v2=v1; i2=i1; v1=noisy; i1=e; }
            else if (noisy > v2) { v2=noisy; i2=e; }
        }
        const float ex = expf(v2 - v1);
        const float p1 = 1.f / (1.f + ex);
        tk[0][t]=p1; tk[1][t]=ex*p1; tk[2][t]=(float)i1; tk[3][t]=(float)i2;
    }
    __syncthreads();
    {
        const int t = tid >> 2, c = tid & 3;
        const float p1 = tk[0][t], p2 = tk[1][t];
        const int i1 = (int)tk[2][t], i2 = (int)tk[3][t];
        float buf[16];
        #pragma unroll
        for (int j = 0; j < 16; ++j) {
            const int e = (c << 4) + j;
            buf[j] = (e == i1) ? p1 : (e == i2) ? p2 : 0.f;
        }
        float* dst = out_r + (size_t)(m0 + t) * NEXP + (c << 4);
        *(float4*)(dst+0)=*(float4*)(buf+0); *(float4*)(dst+4)=*(float4*)(buf+4);
        *(float4*)(dst+8)=*(float4*)(buf+8); *(float4*)(dst+12)=*(float4*)(buf+12);
    }
    if (tid < 64) {
        float2 v = make_float2(tk[2][tid], tk[3][tid]);
        *(float2*)(out_idx + (size_t)(m0 + tid) * 2) = v;
    }
}

extern "C" void kernel_launch(void* const* d_in, const int* in_sizes, int n_in,
                              void* d_out, int out_size, void* d_ws, size_t ws_size,
                              hipStream_t stream) {
    const float* x  = (const float*)d_in[0];
    const float* ep = (const float*)d_in[1];
    const float* Wr = (const float*)d_in[2];
    const float* br = (const float*)d_in[3];
    const float* Wn = (const float*)d_in[4];
    const float* bn = (const float*)d_in[5];

    const int T = in_sizes[1] / NEXP;
    float* out_r   = (float*)d_out;
    float* out_idx = (float*)d_out + (size_t)T * NEXP;

    const size_t limb = (size_t)128 * NEMBD * sizeof(f16);     // 512 KB
    const size_t need = 2 * limb + 256 + (size_t)T * sizeof(int);
    if (ws_size >= need) {
        f16* wt_hi = (f16*)d_ws;
        f16* wt_lo = wt_hi + (size_t)128 * NEMBD;
        int* cnt   = (int*)((char*)d_ws + 2 * limb);
        int* list  = (int*)((char*)d_ws + 2 * limb + 256);

        hipMemsetAsync(cnt, 0, sizeof(int), stream);
        build_wt<<<64, 256, 0, stream>>>(Wr, Wn, wt_hi, wt_lo);
        router_fused8<<<T / TOKB, 512, 0, stream>>>(
            x, ep, wt_hi, br, bn, out_r, out_idx, cnt, list);
        router_fixup<<<512, 128, 0, stream>>>(
            x, ep, wt_hi, wt_lo, br, bn, out_r, out_idx, cnt, list);
    } else {
        router_fused_f32<<<T / 64, 256, 0, stream>>>(
            x, ep, Wr, br, Wn, bn, out_r, out_idx);
    }
}

// Round 11
// 138.009 us; speedup vs baseline: 1.1650x; 1.1650x over previous
//
#include <hip/hip_runtime.h>
#include <math.h>

// NoisyTopKRouter, round 11: canonical LDS-staged MFMA GEMM (coalesced
// global loads ONLY), 1-pass f16-hi + top-3 gap certificate + exact fixup.
// Main: BM=64 x BN=128 x BK=64, 512 thr (8 waves 2x4), grid T/64=256,
// double-buffered LDS; B tile = contiguous 16KB/step copy (wt pre-laid as
// [chunk][kgrp][col][8] so ds_read_b128 frags are conflict-free); A tile
// f32->f16 converted in regs, ds_write_b128.

typedef _Float16 f16;
typedef _Float16 f16x8 __attribute__((ext_vector_type(8)));
typedef float    f32x4 __attribute__((ext_vector_type(4)));

#define NEMBD 2048
#define NEXP  64
#define BM    64
#define BK    64
#define ASTR  72              // XH row stride (f16)
#define LSTR  68              // LG col stride (f32)
#define WSCALE 64.0f
#define INV_WSCALE 0.015625f
#define TAU_C 2.2e-3f

union F4H8 { float4 f; f16x8 h; };

__device__ __forceinline__ f16x8 ld16h(const f16* p) {
    F4H8 u; u.f = *(const float4*)p; return u.h;
}

// ---------- kernel 0: W -> x64-scaled f16 limbs, [chunk][kgrp][col][8] ----------
// element (chunk g, col n, k = kgrp*8+j) at g*4096 + kgrp*1024 + n*8 + j
__global__ __launch_bounds__(256) void build_wt(
    const float* __restrict__ Wr, const float* __restrict__ Wn,
    f16* __restrict__ wt_hi, f16* __restrict__ wt_lo)
{
    __shared__ float ws[32][129];
    const int c = blockIdx.x, t = threadIdx.x;
    const int k0 = c * 32;
    {
        const int k  = t >> 3;
        const int n8 = (t & 7) << 3;
        const float* s0 = Wr + (size_t)(k0 + k) * NEXP + n8;
        const float* s1 = Wn + (size_t)(k0 + k) * NEXP + n8;
        #pragma unroll
        for (int j = 0; j < 8; ++j) ws[k][n8 + j] = s0[j];
        #pragma unroll
        for (int j = 0; j < 8; ++j) ws[k][64 + n8 + j] = s1[j];
    }
    __syncthreads();
    {
        const int n  = t >> 1;           // col 0..127
        const int kh = (t & 1) << 4;     // k base 0 or 16
        const int kg = kh >> 3;          // kgrp 0 or 2
        f16x8 hv0, hv1, lv0, lv1;
        #pragma unroll
        for (int j = 0; j < 8; ++j) {
            const float v = ws[kh + j][n] * WSCALE;
            const f16 h = (f16)v;
            hv0[j] = h; lv0[j] = (f16)(v - (float)h);
        }
        #pragma unroll
        for (int j = 0; j < 8; ++j) {
            const float v = ws[kh + 8 + j][n] * WSCALE;
            const f16 h = (f16)v;
            hv1[j] = h; lv1[j] = (f16)(v - (float)h);
        }
        const size_t b0 = (size_t)c * 4096 + (size_t)kg * 1024 + n * 8;
        *(f16x8*)(wt_hi + b0)        = hv0;
        *(f16x8*)(wt_hi + b0 + 1024) = hv1;
        *(f16x8*)(wt_lo + b0)        = lv0;
        *(f16x8*)(wt_lo + b0 + 1024) = lv1;
    }
}

// ---------- kernel 1: canonical staged MFMA router ----------
__global__ __launch_bounds__(512, 2) void router_fused9(
    const float* __restrict__ x, const float* __restrict__ eps,
    const f16* __restrict__ wt_hi,
    const float* __restrict__ br, const float* __restrict__ bn,
    float* __restrict__ out_r, float* __restrict__ out_idx,
    int* __restrict__ cnt, int* __restrict__ list)
{
    // XH0 @0 (9216B), XH1 @9216, WH0 @18432 (16384B), WH1 @34816; total 51200
    // epilogue overlay: LG[128][68] f32 (34816B) @0 ; TK @51200 (1024B)
    __shared__ __align__(16) char SH[52224];
    f16* XH0 = (f16*)SH;
    f16* XH1 = XH0 + 64 * ASTR;
    f16* WH0 = (f16*)(SH + 18432);
    f16* WH1 = WH0 + 8192;
    float* LG = (float*)SH;
    float* TK = (float*)(SH + 51200);

    const int tid  = threadIdx.x;
    const int lane = tid & 63;
    const int w    = tid >> 6;
    const int wr   = w & 1;              // token half (32)
    const int wc   = w >> 1;             // col quarter (32)
    const int m0   = blockIdx.x * BM;

    const int row16 = lane & 15;
    const int kgrp  = lane >> 4;         // 0..3

    // A stage map: row = tid>>3 (0..63), k offset = (tid&7)*8
    const int srow = tid >> 3;
    const int skof = (tid & 7) << 3;
    const float* axsrc = x + (size_t)(m0 + srow) * NEMBD + skof;
    const int axoff = srow * ASTR + skof;

    // B stage map: 16KB/step contiguous; thread -> 16 f16 at tid*16
    const f16* bsrc = wt_hi + tid * 16;

    // frag offsets
    const int aof0 = (wr * 32 + row16) * ASTR + kgrp * 8;
    const int aof1 = aof0 + 16 * ASTR;
    const int bof0 = kgrp * 1024 + (wc * 32 + row16) * 8;
    const int bof1 = bof0 + 16 * 8;

    f32x4 acc00 = {0.f,0.f,0.f,0.f}, acc01 = {0.f,0.f,0.f,0.f};
    f32x4 acc10 = {0.f,0.f,0.f,0.f}, acc11 = {0.f,0.f,0.f,0.f};

#define CVT8(A0, A1, hv) do { \
    hv[0] = (f16)A0.x; hv[1] = (f16)A0.y; hv[2] = (f16)A0.z; hv[3] = (f16)A0.w; \
    hv[4] = (f16)A1.x; hv[5] = (f16)A1.y; hv[6] = (f16)A1.z; hv[7] = (f16)A1.w; } while (0)

    // prologue: stage step 0 into buf0
    {
        const float4 a0 = *(const float4*)(axsrc);
        const float4 a1 = *(const float4*)(axsrc + 4);
        F4H8 u0, u1;
        u0.f = *(const float4*)(bsrc);
        u1.f = *(const float4*)(bsrc + 8);
        f16x8 hv; CVT8(a0, a1, hv);
        *(f16x8*)(XH0 + axoff) = hv;
        *(f16x8*)(WH0 + tid * 16)     = u0.h;
        *(f16x8*)(WH0 + tid * 16 + 8) = u1.h;
        __syncthreads();
    }

#define STEP(XR, WR, XW, WW, s, doStage) do { \
    float4 a0_, a1_; F4H8 b0_, b1_; \
    if (doStage) { \
        a0_ = *(const float4*)(axsrc + (size_t)((s) + 1) * BK); \
        a1_ = *(const float4*)(axsrc + (size_t)((s) + 1) * BK + 4); \
        b0_.f = *(const float4*)(bsrc + (size_t)((s) + 1) * 8192); \
        b1_.f = *(const float4*)(bsrc + (size_t)((s) + 1) * 8192 + 8); \
        __builtin_amdgcn_sched_barrier(0); \
    } \
    _Pragma("unroll") \
    for (int ks = 0; ks < 2; ++ks) { \
        const f16x8 ah0 = *(const f16x8*)((XR) + aof0 + ks * 32); \
        const f16x8 ah1 = *(const f16x8*)((XR) + aof1 + ks * 32); \
        const f16x8 bh0 = *(const f16x8*)((WR) + ks * 4096 + bof0); \
        const f16x8 bh1 = *(const f16x8*)((WR) + ks * 4096 + bof1); \
        acc00 = __builtin_amdgcn_mfma_f32_16x16x32_f16(ah0, bh0, acc00, 0, 0, 0); \
        acc01 = __builtin_amdgcn_mfma_f32_16x16x32_f16(ah0, bh1, acc01, 0, 0, 0); \
        acc10 = __builtin_amdgcn_mfma_f32_16x16x32_f16(ah1, bh0, acc10, 0, 0, 0); \
        acc11 = __builtin_amdgcn_mfma_f32_16x16x32_f16(ah1, bh1, acc11, 0, 0, 0); \
    } \
    if (doStage) { \
        f16x8 hv_; CVT8(a0_, a1_, hv_); \
        *(f16x8*)((XW) + axoff) = hv_; \
        *(f16x8*)((WW) + tid * 16)     = b0_.h; \
        *(f16x8*)((WW) + tid * 16 + 8) = b1_.h; \
    } \
    __syncthreads(); \
} while (0)

    for (int s = 0; s < 32; s += 2) {
        STEP(XH0, WH0, XH1, WH1, s,     (s + 1) < 32);
        STEP(XH1, WH1, XH0, WH0, s + 1, (s + 2) < 32);
    }
#undef STEP
#undef CVT8

    // ---- epilogue: descale + bias, logits -> LG overlay ----
    {
        const int tokb = kgrp << 2;
        #pragma unroll
        for (int fj = 0; fj < 4; ++fj) {
            const int i = fj >> 1, j = fj & 1;
            const int col = wc * 32 + j * 16 + row16;
            const int tok = wr * 32 + i * 16 + tokb;
            const float bias = (col < NEXP) ? br[col] : bn[col - NEXP];
            const f32x4 a = (fj == 0) ? acc00 : (fj == 1) ? acc01 : (fj == 2) ? acc10 : acc11;
            #pragma unroll
            for (int r = 0; r < 4; ++r)
                LG[col * LSTR + tok + r] = a[r] * INV_WSCALE + bias;
        }
    }
    __syncthreads();

    // ---- bias + noise + top-3 + certification: 4 lanes per token ----
    if (tid < 256) {
        const int t = tid >> 2;          // token 0..63
        const int q = tid & 3;           // expert quarter
        const float* ep = eps + (size_t)(m0 + t) * NEXP;
        float v1 = -1e30f, v2 = -1e30f, v3 = -1e30f;
        int i1 = 0, i2 = 0, i3 = 0;
        float mx = 0.f;
        for (int j = 0; j < 16; ++j) {
            const int e = q * 16 + j;
            const float r  = LG[e * LSTR + t];
            const float nr = LG[(NEXP + e) * LSTR + t];
            const float sp = fmaxf(nr, 0.f) + log1pf(expf(-fabsf(nr)));
            const float ev = ep[e];
            mx = fmaxf(mx, fabsf(ev));
            const float noisy = fmaf(ev, sp, r);
            if (noisy > v1) { v3 = v2; i3 = i2; v2 = v1; i2 = i1; v1 = noisy; i1 = e; }
            else if (noisy > v2) { v3 = v2; i3 = i2; v2 = noisy; i2 = e; }
            else if (noisy > v3) { v3 = noisy; i3 = e; }
        }
        #pragma unroll
        for (int s = 0; s < 2; ++s) {
            const int dist = 1 << s;
            const float ov1 = __shfl_xor(v1, dist);
            const float ov2 = __shfl_xor(v2, dist);
            const float ov3 = __shfl_xor(v3, dist);
            const int   oi1 = __shfl_xor(i1, dist);
            const int   oi2 = __shfl_xor(i2, dist);
            const int   oi3 = __shfl_xor(i3, dist);
            mx = fmaxf(mx, __shfl_xor(mx, dist));
            const int h = (q >> s) & 1;
            float a1, a2, a3, bb1, bb2, bb3; int ai1, ai2, ai3, bj1, bj2, bj3;
            if (h) { a1=ov1;a2=ov2;a3=ov3;ai1=oi1;ai2=oi2;ai3=oi3;
                     bb1=v1;bb2=v2;bb3=v3;bj1=i1;bj2=i2;bj3=i3; }
            else   { a1=v1;a2=v2;a3=v3;ai1=i1;ai2=i2;ai3=i3;
                     bb1=ov1;bb2=ov2;bb3=ov3;bj1=oi1;bj2=oi2;bj3=oi3; }
            #pragma unroll
            for (int bi = 0; bi < 3; ++bi) {
                const float bv = (bi == 0) ? bb1 : (bi == 1) ? bb2 : bb3;
                const int   bj = (bi == 0) ? bj1 : (bi == 1) ? bj2 : bj3;
                if (bv > a1) { a3=a2;ai3=ai2; a2=a1;ai2=ai1; a1=bv;ai1=bj; }
                else if (bv > a2) { a3=a2;ai3=ai2; a2=bv;ai2=bj; }
                else if (bv > a3) { a3=bv;ai3=bj; }
            }
            v1=a1;v2=a2;v3=a3;i1=ai1;i2=ai2;i3=ai3;
        }
        if (q == 0) {
            const float e1 = fabsf(ep[i1]);
            const float e2 = fabsf(ep[i2]);
            const float em = fmaxf(e1, e2);
            const float t12 = TAU_C * sqrtf(2.f + e1 * e1 + e2 * e2);
            const float t23 = TAU_C * sqrtf(2.f + em * em + mx * mx);
            if ((v1 - v2 < t12) || (v2 - v3 < t23)) {
                const int ai = atomicAdd(cnt, 1);
                list[ai] = m0 + t;
            }
            const float ex = expf(v2 - v1);
            const float p1 = 1.f / (1.f + ex);
            TK[0 * BM + t] = p1;
            TK[1 * BM + t] = ex * p1;
            TK[2 * BM + t] = (float)i1;
            TK[3 * BM + t] = (float)i2;
        }
    }
    __syncthreads();

    // ---- write r_out (8 floats/thread) + idx ----
    {
        const int t  = tid >> 3;            // 0..63
        const int c8 = (tid & 7) << 3;      // 0..56
        const float p1 = TK[t], p2 = TK[BM + t];
        const int i1 = (int)TK[2 * BM + t], i2 = (int)TK[3 * BM + t];
        float buf[8];
        #pragma unroll
        for (int jj = 0; jj < 8; ++jj) {
            const int e = c8 + jj;
            buf[jj] = (e == i1) ? p1 : (e == i2) ? p2 : 0.f;
        }
        float* dst = out_r + (size_t)(m0 + t) * NEXP + c8;
        *(float4*)(dst + 0) = *(float4*)(buf + 0);
        *(float4*)(dst + 4) = *(float4*)(buf + 4);
    }
    if (tid < BM) {
        float2 v = make_float2(TK[2 * BM + tid], TK[3 * BM + tid]);
        *(float2*)(out_idx + (size_t)(m0 + tid) * 2) = v;
    }
}

// ---------- kernel 2: exact f32 fixup, 4 threads per col ----------
__global__ __launch_bounds__(512) void router_fixup(
    const float* __restrict__ x, const float* __restrict__ eps,
    const f16* __restrict__ wt_hi, const f16* __restrict__ wt_lo,
    const float* __restrict__ br, const float* __restrict__ bn,
    float* __restrict__ out_r, float* __restrict__ out_idx,
    const int* __restrict__ cnt, const int* __restrict__ list)
{
    __shared__ __align__(16) float xs[NEMBD];
    __shared__ float lg[128];
    __shared__ float tk[4];

    const int tid = threadIdx.x;
    const int n = cnt[0];
    for (int it = blockIdx.x; it < n; it += gridDim.x) {
        const int tok = list[it];
        {   // stage x row: 512 thr x float4
            const float4* src = (const float4*)(x + (size_t)tok * NEMBD);
            ((float4*)xs)[tid] = src[tid];
        }
        __syncthreads();
        {   // col = tid>>2, q = tid&3: 512-K partial, shuffle-reduce
            const int col = tid >> 2;
            const int q = tid & 3;
            float a = 0.f;
            for (int gg = 0; gg < 16; ++gg) {
                const int g = q * 16 + gg;
                const float* xr = xs + g * 32;
                #pragma unroll
                for (int kg = 0; kg < 4; ++kg) {
                    const size_t o = (size_t)g * 4096 + kg * 1024 + col * 8;
                    const f16x8 hv = ld16h(wt_hi + o);
                    const f16x8 lv = ld16h(wt_lo + o);
                    #pragma unroll
                    for (int j = 0; j < 8; ++j)
                        a = fmaf(xr[kg * 8 + j], (float)hv[j] + (float)lv[j], a);
                }
            }
            a += __shfl_xor(a, 1);
            a += __shfl_xor(a, 2);
            if (q == 0) {
                const float bias = (col < NEXP) ? br[col] : bn[col - NEXP];
                lg[col] = a * INV_WSCALE + bias;
            }
        }
        __syncthreads();
        if (tid == 0) {
            const float* ep = eps + (size_t)tok * NEXP;
            float v1 = -1e30f, v2 = -1e30f;
            int i1 = 0, i2 = 0;
            for (int e = 0; e < NEXP; ++e) {
                const float r  = lg[e];
                const float nr = lg[NEXP + e];
                const float sp = fmaxf(nr, 0.f) + log1pf(expf(-fabsf(nr)));
                const float noisy = fmaf(ep[e], sp, r);
                if (noisy > v1) { v2 = v1; i2 = i1; v1 = noisy; i1 = e; }
                else if (noisy > v2) { v2 = noisy; i2 = e; }
            }
            const float ex = expf(v2 - v1);
            const float p1 = 1.f / (1.f + ex);
            tk[0] = p1; tk[1] = ex * p1;
            tk[2] = (float)i1; tk[3] = (float)i2;
        }
        __syncthreads();
        if (tid < NEXP) {
            const int i1 = (int)tk[2], i2 = (int)tk[3];
            out_r[(size_t)tok * NEXP + tid] =
                (tid == i1) ? tk[0] : (tid == i2) ? tk[1] : 0.f;
        }
        if (tid == 0) {
            *(float2*)(out_idx + (size_t)tok * 2) = make_float2(tk[2], tk[3]);
        }
        __syncthreads();
    }
}

// ---------- fallback: fused f32 kernel (insurance only) ----------
__global__ __launch_bounds__(256) void router_fused_f32(
    const float* __restrict__ x, const float* __restrict__ eps,
    const float* __restrict__ Wr, const float* __restrict__ br,
    const float* __restrict__ Wn, const float* __restrict__ bn,
    float* __restrict__ out_r, float* __restrict__ out_idx)
{
    __shared__ float xsm[32][64];
    __shared__ float ws2[32][128];
    __shared__ float lg[128][64];
    __shared__ float tk[4][64];
    const int tid = threadIdx.x;
    const int tx = tid & 15, ty = tid >> 4;
    const int m0 = blockIdx.x * 64;
    float acc[4][8];
    #pragma unroll
    for (int i = 0; i < 4; ++i)
        #pragma unroll
        for (int j = 0; j < 8; ++j) acc[i][j] = 0.f;
    for (int kc = 0; kc < NEMBD; kc += 32) {
        {
            const int tm = tid >> 2, kk = (tid & 3) << 3;
            const float* src = x + (size_t)(m0 + tm) * NEMBD + kc + kk;
            const float4 a = *(const float4*)(src);
            const float4 b = *(const float4*)(src + 4);
            xsm[kk+0][tm]=a.x; xsm[kk+1][tm]=a.y; xsm[kk+2][tm]=a.z; xsm[kk+3][tm]=a.w;
            xsm[kk+4][tm]=b.x; xsm[kk+5][tm]=b.y; xsm[kk+6][tm]=b.z; xsm[kk+7][tm]=b.w;
        }
        {
            const int kr = tid >> 3, q = tid & 7;
            const float* src = (q < 4)
                ? (Wr + (size_t)(kc + kr) * NEXP + (q << 4))
                : (Wn + (size_t)(kc + kr) * NEXP + ((q - 4) << 4));
            float* dst = &ws2[kr][q << 4];
            #pragma unroll
            for (int j = 0; j < 16; ++j) dst[j] = src[j];
        }
        __syncthreads();
        #pragma unroll
        for (int k = 0; k < 32; ++k) {
            const float4 xv = *(const float4*)&xsm[k][ty << 2];
            const float4 wa = *(const float4*)&ws2[k][tx << 3];
            const float4 wb = *(const float4*)&ws2[k][(tx << 3) + 4];
            const float xr[4] = {xv.x, xv.y, xv.z, xv.w};
            const float wcx[8] = {wa.x, wa.y, wa.z, wa.w, wb.x, wb.y, wb.z, wb.w};
            #pragma unroll
            for (int i = 0; i < 4; ++i)
                #pragma unroll
                for (int j = 0; j < 8; ++j)
                    acc[i][j] = fmaf(xr[i], wcx[j], acc[i][j]);
        }
        __syncthreads();
    }
    {
        const int n0 = tx << 3;
        #pragma unroll
        for (int j = 0; j < 8; ++j) {
            const int nn = n0 + j;
            const float b = (nn < NEXP) ? br[nn] : bn[nn - NEXP];
            #pragma unroll
            for (int i = 0; i < 4; ++i)
                lg[nn][(ty << 2) + i] = acc[i][j] + b;
        }
    }
    __syncthreads();
    if (tid < 64) {
        const int t = tid;
        const float* ep = eps + (size_t)(m0 + t) * NEXP;
        float v1 = -1e30f, v2 = -1e30f; int i1 = 0, i2 = 0;
        for (int e = 0; e < NEXP; ++e) {
            const float r = lg[e][t], nr = lg[NEXP + e][t];
            const float sp = fmaxf(nr, 0.f) + log1pf(expf(-fabsf(nr)));
            const float noisy = fmaf(ep[e], sp, r);
            if (noisy > v1) { v2=v1; i2=i1; v1=noisy; i1=e; }
            else if (noisy > v2) { v2=noisy; i2=e; }
        }
        const float ex = expf(v2 - v1);
        const float p1 = 1.f / (1.f + ex);
        tk[0][t]=p1; tk[1][t]=ex*p1; tk[2][t]=(float)i1; tk[3][t]=(float)i2;
    }
    __syncthreads();
    {
        const int t = tid >> 2, c = tid & 3;
        const float p1 = tk[0][t], p2 = tk[1][t];
        const int i1 = (int)tk[2][t], i2 = (int)tk[3][t];
        float buf[16];
        #pragma unroll
        for (int j = 0; j < 16; ++j) {
            const int e = (c << 4) + j;
            buf[j] = (e == i1) ? p1 : (e == i2) ? p2 : 0.f;
        }
        float* dst = out_r + (size_t)(m0 + t) * NEXP + (c << 4);
        *(float4*)(dst+0)=*(float4*)(buf+0); *(float4*)(dst+4)=*(float4*)(buf+4);
        *(float4*)(dst+8)=*(float4*)(buf+8); *(float4*)(dst+12)=*(float4*)(buf+12);
    }
    if (tid < 64) {
        float2 v = make_float2(tk[2][tid], tk[3][tid]);
        *(float2*)(out_idx + (size_t)(m0 + tid) * 2) = v;
    }
}

extern "C" void kernel_launch(void* const* d_in, const int* in_sizes, int n_in,
                              void* d_out, int out_size, void* d_ws, size_t ws_size,
                              hipStream_t stream) {
    const float* x  = (const float*)d_in[0];
    const float* ep = (const float*)d_in[1];
    const float* Wr = (const float*)d_in[2];
    const float* br = (const float*)d_in[3];
    const float* Wn = (const float*)d_in[4];
    const float* bn = (const float*)d_in[5];

    const int T = in_sizes[1] / NEXP;
    float* out_r   = (float*)d_out;
    float* out_idx = (float*)d_out + (size_t)T * NEXP;

    const size_t limb = (size_t)128 * NEMBD * sizeof(f16);     // 512 KB
    const size_t need = 2 * limb + 256 + (size_t)T * sizeof(int);
    if (ws_size >= need) {
        f16* wt_hi = (f16*)d_ws;
        f16* wt_lo = wt_hi + (size_t)128 * NEMBD;
        int* cnt   = (int*)((char*)d_ws + 2 * limb);
        int* list  = (int*)((char*)d_ws + 2 * limb + 256);

        hipMemsetAsync(cnt, 0, sizeof(int), stream);
        build_wt<<<64, 256, 0, stream>>>(Wr, Wn, wt_hi, wt_lo);
        router_fused9<<<T / BM, 512, 0, stream>>>(
            x, ep, wt_hi, br, bn, out_r, out_idx, cnt, list);
        router_fixup<<<512, 512, 0, stream>>>(
            x, ep, wt_hi, wt_lo, br, bn, out_r, out_idx, cnt, list);
    } else {
        router_fused_f32<<<T / 64, 256, 0, stream>>>(
            x, ep, Wr, br, Wn, bn, out_r, out_idx);
    }
}

// Round 12
// 105.164 us; speedup vs baseline: 1.5289x; 1.3123x over previous
//
#include <hip/hip_runtime.h>
#include <math.h>

// NoisyTopKRouter, round 12: canonical LDS-staged MFMA GEMM (round 11)
// + fixup rewritten as a gathered mini-GEMM (3-limb exact) over flagged
// tokens — replaces the 90us serial-chain fixup.

typedef _Float16 f16;
typedef _Float16 f16x8 __attribute__((ext_vector_type(8)));
typedef float    f32x4 __attribute__((ext_vector_type(4)));

#define NEMBD 2048
#define NEXP  64
#define BM    64
#define BK    64
#define ASTR  72              // XH row stride (f16)
#define LSTR  68              // LG col stride (f32)
#define WSCALE 64.0f
#define INV_WSCALE 0.015625f
#define TAU_C 2.2e-3f

union F4H8 { float4 f; f16x8 h; };

__device__ __forceinline__ f16x8 ld16h(const f16* p) {
    F4H8 u; u.f = *(const float4*)p; return u.h;
}

// ---------- kernel 0: W -> x64-scaled f16 limbs, [chunk][kgrp][col][8] ----------
__global__ __launch_bounds__(256) void build_wt(
    const float* __restrict__ Wr, const float* __restrict__ Wn,
    f16* __restrict__ wt_hi, f16* __restrict__ wt_lo)
{
    __shared__ float ws[32][129];
    const int c = blockIdx.x, t = threadIdx.x;
    const int k0 = c * 32;
    {
        const int k  = t >> 3;
        const int n8 = (t & 7) << 3;
        const float* s0 = Wr + (size_t)(k0 + k) * NEXP + n8;
        const float* s1 = Wn + (size_t)(k0 + k) * NEXP + n8;
        #pragma unroll
        for (int j = 0; j < 8; ++j) ws[k][n8 + j] = s0[j];
        #pragma unroll
        for (int j = 0; j < 8; ++j) ws[k][64 + n8 + j] = s1[j];
    }
    __syncthreads();
    {
        const int n  = t >> 1;           // col 0..127
        const int kh = (t & 1) << 4;     // k base 0 or 16
        const int kg = kh >> 3;          // kgrp 0 or 2
        f16x8 hv0, hv1, lv0, lv1;
        #pragma unroll
        for (int j = 0; j < 8; ++j) {
            const float v = ws[kh + j][n] * WSCALE;
            const f16 h = (f16)v;
            hv0[j] = h; lv0[j] = (f16)(v - (float)h);
        }
        #pragma unroll
        for (int j = 0; j < 8; ++j) {
            const float v = ws[kh + 8 + j][n] * WSCALE;
            const f16 h = (f16)v;
            hv1[j] = h; lv1[j] = (f16)(v - (float)h);
        }
        const size_t b0 = (size_t)c * 4096 + (size_t)kg * 1024 + n * 8;
        *(f16x8*)(wt_hi + b0)        = hv0;
        *(f16x8*)(wt_hi + b0 + 1024) = hv1;
        *(f16x8*)(wt_lo + b0)        = lv0;
        *(f16x8*)(wt_lo + b0 + 1024) = lv1;
    }
}

// ---------- kernel 1: canonical staged MFMA router (round 11, unchanged) ----------
__global__ __launch_bounds__(512, 2) void router_fused9(
    const float* __restrict__ x, const float* __restrict__ eps,
    const f16* __restrict__ wt_hi,
    const float* __restrict__ br, const float* __restrict__ bn,
    float* __restrict__ out_r, float* __restrict__ out_idx,
    int* __restrict__ cnt, int* __restrict__ list)
{
    __shared__ __align__(16) char SH[52224];
    f16* XH0 = (f16*)SH;
    f16* XH1 = XH0 + 64 * ASTR;
    f16* WH0 = (f16*)(SH + 18432);
    f16* WH1 = WH0 + 8192;
    float* LG = (float*)SH;
    float* TK = (float*)(SH + 51200);

    const int tid  = threadIdx.x;
    const int lane = tid & 63;
    const int w    = tid >> 6;
    const int wr   = w & 1;
    const int wc   = w >> 1;
    const int m0   = blockIdx.x * BM;

    const int row16 = lane & 15;
    const int kgrp  = lane >> 4;

    const int srow = tid >> 3;
    const int skof = (tid & 7) << 3;
    const float* axsrc = x + (size_t)(m0 + srow) * NEMBD + skof;
    const int axoff = srow * ASTR + skof;

    const f16* bsrc = wt_hi + tid * 16;

    const int aof0 = (wr * 32 + row16) * ASTR + kgrp * 8;
    const int aof1 = aof0 + 16 * ASTR;
    const int bof0 = kgrp * 1024 + (wc * 32 + row16) * 8;
    const int bof1 = bof0 + 16 * 8;

    f32x4 acc00 = {0.f,0.f,0.f,0.f}, acc01 = {0.f,0.f,0.f,0.f};
    f32x4 acc10 = {0.f,0.f,0.f,0.f}, acc11 = {0.f,0.f,0.f,0.f};

#define CVT8(A0, A1, hv) do { \
    hv[0] = (f16)A0.x; hv[1] = (f16)A0.y; hv[2] = (f16)A0.z; hv[3] = (f16)A0.w; \
    hv[4] = (f16)A1.x; hv[5] = (f16)A1.y; hv[6] = (f16)A1.z; hv[7] = (f16)A1.w; } while (0)

    {
        const float4 a0 = *(const float4*)(axsrc);
        const float4 a1 = *(const float4*)(axsrc + 4);
        F4H8 u0, u1;
        u0.f = *(const float4*)(bsrc);
        u1.f = *(const float4*)(bsrc + 8);
        f16x8 hv; CVT8(a0, a1, hv);
        *(f16x8*)(XH0 + axoff) = hv;
        *(f16x8*)(WH0 + tid * 16)     = u0.h;
        *(f16x8*)(WH0 + tid * 16 + 8) = u1.h;
        __syncthreads();
    }

#define STEP(XR, WR, XW, WW, s, doStage) do { \
    float4 a0_, a1_; F4H8 b0_, b1_; \
    if (doStage) { \
        a0_ = *(const float4*)(axsrc + (size_t)((s) + 1) * BK); \
        a1_ = *(const float4*)(axsrc + (size_t)((s) + 1) * BK + 4); \
        b0_.f = *(const float4*)(bsrc + (size_t)((s) + 1) * 8192); \
        b1_.f = *(const float4*)(bsrc + (size_t)((s) + 1) * 8192 + 8); \
        __builtin_amdgcn_sched_barrier(0); \
    } \
    _Pragma("unroll") \
    for (int ks = 0; ks < 2; ++ks) { \
        const f16x8 ah0 = *(const f16x8*)((XR) + aof0 + ks * 32); \
        const f16x8 ah1 = *(const f16x8*)((XR) + aof1 + ks * 32); \
        const f16x8 bh0 = *(const f16x8*)((WR) + ks * 4096 + bof0); \
        const f16x8 bh1 = *(const f16x8*)((WR) + ks * 4096 + bof1); \
        acc00 = __builtin_amdgcn_mfma_f32_16x16x32_f16(ah0, bh0, acc00, 0, 0, 0); \
        acc01 = __builtin_amdgcn_mfma_f32_16x16x32_f16(ah0, bh1, acc01, 0, 0, 0); \
        acc10 = __builtin_amdgcn_mfma_f32_16x16x32_f16(ah1, bh0, acc10, 0, 0, 0); \
        acc11 = __builtin_amdgcn_mfma_f32_16x16x32_f16(ah1, bh1, acc11, 0, 0, 0); \
    } \
    if (doStage) { \
        f16x8 hv_; CVT8(a0_, a1_, hv_); \
        *(f16x8*)((XW) + axoff) = hv_; \
        *(f16x8*)((WW) + tid * 16)     = b0_.h; \
        *(f16x8*)((WW) + tid * 16 + 8) = b1_.h; \
    } \
    __syncthreads(); \
} while (0)

    for (int s = 0; s < 32; s += 2) {
        STEP(XH0, WH0, XH1, WH1, s,     (s + 1) < 32);
        STEP(XH1, WH1, XH0, WH0, s + 1, (s + 2) < 32);
    }
#undef STEP

    {
        const int tokb = kgrp << 2;
        #pragma unroll
        for (int fj = 0; fj < 4; ++fj) {
            const int i = fj >> 1, j = fj & 1;
            const int col = wc * 32 + j * 16 + row16;
            const int tok = wr * 32 + i * 16 + tokb;
            const float bias = (col < NEXP) ? br[col] : bn[col - NEXP];
            const f32x4 a = (fj == 0) ? acc00 : (fj == 1) ? acc01 : (fj == 2) ? acc10 : acc11;
            #pragma unroll
            for (int r = 0; r < 4; ++r)
                LG[col * LSTR + tok + r] = a[r] * INV_WSCALE + bias;
        }
    }
    __syncthreads();

    if (tid < 256) {
        const int t = tid >> 2;
        const int q = tid & 3;
        const float* ep = eps + (size_t)(m0 + t) * NEXP;
        float v1 = -1e30f, v2 = -1e30f, v3 = -1e30f;
        int i1 = 0, i2 = 0, i3 = 0;
        float mx = 0.f;
        for (int j = 0; j < 16; ++j) {
            const int e = q * 16 + j;
            const float r  = LG[e * LSTR + t];
            const float nr = LG[(NEXP + e) * LSTR + t];
            const float sp = fmaxf(nr, 0.f) + log1pf(expf(-fabsf(nr)));
            const float ev = ep[e];
            mx = fmaxf(mx, fabsf(ev));
            const float noisy = fmaf(ev, sp, r);
            if (noisy > v1) { v3 = v2; i3 = i2; v2 = v1; i2 = i1; v1 = noisy; i1 = e; }
            else if (noisy > v2) { v3 = v2; i3 = i2; v2 = noisy; i2 = e; }
            else if (noisy > v3) { v3 = noisy; i3 = e; }
        }
        #pragma unroll
        for (int s = 0; s < 2; ++s) {
            const int dist = 1 << s;
            const float ov1 = __shfl_xor(v1, dist);
            const float ov2 = __shfl_xor(v2, dist);
            const float ov3 = __shfl_xor(v3, dist);
            const int   oi1 = __shfl_xor(i1, dist);
            const int   oi2 = __shfl_xor(i2, dist);
            const int   oi3 = __shfl_xor(i3, dist);
            mx = fmaxf(mx, __shfl_xor(mx, dist));
            const int h = (q >> s) & 1;
            float a1, a2, a3, bb1, bb2, bb3; int ai1, ai2, ai3, bj1, bj2, bj3;
            if (h) { a1=ov1;a2=ov2;a3=ov3;ai1=oi1;ai2=oi2;ai3=oi3;
                     bb1=v1;bb2=v2;bb3=v3;bj1=i1;bj2=i2;bj3=i3; }
            else   { a1=v1;a2=v2;a3=v3;ai1=i1;ai2=i2;ai3=i3;
                     bb1=ov1;bb2=ov2;bb3=ov3;bj1=oi1;bj2=oi2;bj3=oi3; }
            #pragma unroll
            for (int bi = 0; bi < 3; ++bi) {
                const float bv = (bi == 0) ? bb1 : (bi == 1) ? bb2 : bb3;
                const int   bj = (bi == 0) ? bj1 : (bi == 1) ? bj2 : bj3;
                if (bv > a1) { a3=a2;ai3=ai2; a2=a1;ai2=ai1; a1=bv;ai1=bj; }
                else if (bv > a2) { a3=a2;ai3=ai2; a2=bv;ai2=bj; }
                else if (bv > a3) { a3=bv;ai3=bj; }
            }
            v1=a1;v2=a2;v3=a3;i1=ai1;i2=ai2;i3=ai3;
        }
        if (q == 0) {
            const float e1 = fabsf(ep[i1]);
            const float e2 = fabsf(ep[i2]);
            const float em = fmaxf(e1, e2);
            const float t12 = TAU_C * sqrtf(2.f + e1 * e1 + e2 * e2);
            const float t23 = TAU_C * sqrtf(2.f + em * em + mx * mx);
            if ((v1 - v2 < t12) || (v2 - v3 < t23)) {
                const int ai = atomicAdd(cnt, 1);
                list[ai] = m0 + t;
            }
            const float ex = expf(v2 - v1);
            const float p1 = 1.f / (1.f + ex);
            TK[0 * BM + t] = p1;
            TK[1 * BM + t] = ex * p1;
            TK[2 * BM + t] = (float)i1;
            TK[3 * BM + t] = (float)i2;
        }
    }
    __syncthreads();

    {
        const int t  = tid >> 3;
        const int c8 = (tid & 7) << 3;
        const float p1 = TK[t], p2 = TK[BM + t];
        const int i1 = (int)TK[2 * BM + t], i2 = (int)TK[3 * BM + t];
        float buf[8];
        #pragma unroll
        for (int jj = 0; jj < 8; ++jj) {
            const int e = c8 + jj;
            buf[jj] = (e == i1) ? p1 : (e == i2) ? p2 : 0.f;
        }
        float* dst = out_r + (size_t)(m0 + t) * NEXP + c8;
        *(float4*)(dst + 0) = *(float4*)(buf + 0);
        *(float4*)(dst + 4) = *(float4*)(buf + 4);
    }
    if (tid < BM) {
        float2 v = make_float2(TK[2 * BM + tid], TK[3 * BM + tid]);
        *(float2*)(out_idx + (size_t)(m0 + tid) * 2) = v;
    }
}

// ---------- kernel 2: gathered mini-GEMM fixup (3-limb exact) ----------
// Grid 256; block b handles flagged tokens list[b*64 .. b*64+63].
// Same canonical staging as fused9, single-buffered, hi+lo limbs.
__global__ __launch_bounds__(512, 2) void router_fixup2(
    const float* __restrict__ x, const float* __restrict__ eps,
    const f16* __restrict__ wt_hi, const f16* __restrict__ wt_lo,
    const float* __restrict__ br, const float* __restrict__ bn,
    float* __restrict__ out_r, float* __restrict__ out_idx,
    const int* __restrict__ cnt, const int* __restrict__ list)
{
    __shared__ __align__(16) char SH[52480];
    f16* XH = (f16*)SH;                      // [64][72]
    f16* XL = XH + 64 * ASTR;                // @9216
    f16* WH = (f16*)(SH + 18432);            // 8192 f16
    f16* WL = WH + 8192;                     // @34816
    float* LG = (float*)SH;                  // overlay (epilogue)
    float* TK = (float*)(SH + 51200);
    int*   LT = (int*)(SH + 52224);          // token indices [64]

    const int n  = cnt[0];
    const int m0 = blockIdx.x * BM;
    if (m0 >= n) return;

    const int tid  = threadIdx.x;
    const int lane = tid & 63;
    const int w    = tid >> 6;
    const int wr   = w & 1;
    const int wc   = w >> 1;

    if (tid < BM) LT[tid] = (m0 + tid < n) ? list[m0 + tid] : -1;
    __syncthreads();

    const int row16 = lane & 15;
    const int kgrp  = lane >> 4;

    const int srow = tid >> 3;
    const int skof = (tid & 7) << 3;
    const int tok_s = (LT[srow] >= 0) ? LT[srow] : LT[0];
    const float* axsrc = x + (size_t)tok_s * NEMBD + skof;
    const int axoff = srow * ASTR + skof;

    const f16* bsrc_h = wt_hi + tid * 16;
    const f16* bsrc_l = wt_lo + tid * 16;

    const int aof0 = (wr * 32 + row16) * ASTR + kgrp * 8;
    const int aof1 = aof0 + 16 * ASTR;
    const int bof0 = kgrp * 1024 + (wc * 32 + row16) * 8;
    const int bof1 = bof0 + 16 * 8;

    f32x4 acc00 = {0.f,0.f,0.f,0.f}, acc01 = {0.f,0.f,0.f,0.f};
    f32x4 acc10 = {0.f,0.f,0.f,0.f}, acc11 = {0.f,0.f,0.f,0.f};

    for (int s = 0; s < 32; ++s) {
        const float4 a0 = *(const float4*)(axsrc + (size_t)s * BK);
        const float4 a1 = *(const float4*)(axsrc + (size_t)s * BK + 4);
        F4H8 bh0_, bh1_, bl0_, bl1_;
        bh0_.f = *(const float4*)(bsrc_h + (size_t)s * 8192);
        bh1_.f = *(const float4*)(bsrc_h + (size_t)s * 8192 + 8);
        bl0_.f = *(const float4*)(bsrc_l + (size_t)s * 8192);
        bl1_.f = *(const float4*)(bsrc_l + (size_t)s * 8192 + 8);
        f16x8 hv, lv;
        {
            const float av[8] = {a0.x, a0.y, a0.z, a0.w, a1.x, a1.y, a1.z, a1.w};
            #pragma unroll
            for (int j = 0; j < 8; ++j) {
                const f16 h = (f16)av[j];
                hv[j] = h; lv[j] = (f16)(av[j] - (float)h);
            }
        }
        *(f16x8*)(XH + axoff) = hv;
        *(f16x8*)(XL + axoff) = lv;
        *(f16x8*)(WH + tid * 16)     = bh0_.h;
        *(f16x8*)(WH + tid * 16 + 8) = bh1_.h;
        *(f16x8*)(WL + tid * 16)     = bl0_.h;
        *(f16x8*)(WL + tid * 16 + 8) = bl1_.h;
        __syncthreads();
        #pragma unroll
        for (int ks = 0; ks < 2; ++ks) {
            const f16x8 ah0 = *(const f16x8*)(XH + aof0 + ks * 32);
            const f16x8 al0 = *(const f16x8*)(XL + aof0 + ks * 32);
            const f16x8 ah1 = *(const f16x8*)(XH + aof1 + ks * 32);
            const f16x8 al1 = *(const f16x8*)(XL + aof1 + ks * 32);
            const f16x8 bh0 = *(const f16x8*)(WH + ks * 4096 + bof0);
            const f16x8 bh1 = *(const f16x8*)(WH + ks * 4096 + bof1);
            const f16x8 bl0 = *(const f16x8*)(WL + ks * 4096 + bof0);
            const f16x8 bl1 = *(const f16x8*)(WL + ks * 4096 + bof1);
            acc00 = __builtin_amdgcn_mfma_f32_16x16x32_f16(ah0, bh0, acc00, 0, 0, 0);
            acc00 = __builtin_amdgcn_mfma_f32_16x16x32_f16(al0, bh0, acc00, 0, 0, 0);
            acc00 = __builtin_amdgcn_mfma_f32_16x16x32_f16(ah0, bl0, acc00, 0, 0, 0);
            acc01 = __builtin_amdgcn_mfma_f32_16x16x32_f16(ah0, bh1, acc01, 0, 0, 0);
            acc01 = __builtin_amdgcn_mfma_f32_16x16x32_f16(al0, bh1, acc01, 0, 0, 0);
            acc01 = __builtin_amdgcn_mfma_f32_16x16x32_f16(ah0, bl1, acc01, 0, 0, 0);
            acc10 = __builtin_amdgcn_mfma_f32_16x16x32_f16(ah1, bh0, acc10, 0, 0, 0);
            acc10 = __builtin_amdgcn_mfma_f32_16x16x32_f16(al1, bh0, acc10, 0, 0, 0);
            acc10 = __builtin_amdgcn_mfma_f32_16x16x32_f16(ah1, bl0, acc10, 0, 0, 0);
            acc11 = __builtin_amdgcn_mfma_f32_16x16x32_f16(ah1, bh1, acc11, 0, 0, 0);
            acc11 = __builtin_amdgcn_mfma_f32_16x16x32_f16(al1, bh1, acc11, 0, 0, 0);
            acc11 = __builtin_amdgcn_mfma_f32_16x16x32_f16(ah1, bl1, acc11, 0, 0, 0);
        }
        __syncthreads();
    }

    // epilogue: logits -> LG overlay
    {
        const int tokb = kgrp << 2;
        #pragma unroll
        for (int fj = 0; fj < 4; ++fj) {
            const int i = fj >> 1, j = fj & 1;
            const int col = wc * 32 + j * 16 + row16;
            const int tok = wr * 32 + i * 16 + tokb;
            const float bias = (col < NEXP) ? br[col] : bn[col - NEXP];
            const f32x4 a = (fj == 0) ? acc00 : (fj == 1) ? acc01 : (fj == 2) ? acc10 : acc11;
            #pragma unroll
            for (int r = 0; r < 4; ++r)
                LG[col * LSTR + tok + r] = a[r] * INV_WSCALE + bias;
        }
    }
    __syncthreads();

    // top-2: 4 lanes per token
    if (tid < 256) {
        const int t = tid >> 2;
        const int q = tid & 3;
        const int tok = LT[t];
        const float* ep = eps + (size_t)(tok >= 0 ? tok : LT[0]) * NEXP;
        float v1 = -1e30f, v2 = -1e30f;
        int i1 = 0, i2 = 0;
        for (int j = 0; j < 16; ++j) {
            const int e = q * 16 + j;
            const float r  = LG[e * LSTR + t];
            const float nr = LG[(NEXP + e) * LSTR + t];
            const float sp = fmaxf(nr, 0.f) + log1pf(expf(-fabsf(nr)));
            const float noisy = fmaf(ep[e], sp, r);
            if (noisy > v1) { v2 = v1; i2 = i1; v1 = noisy; i1 = e; }
            else if (noisy > v2) { v2 = noisy; i2 = e; }
        }
        #pragma unroll
        for (int s = 0; s < 2; ++s) {
            const int dist = 1 << s;
            const float ov1 = __shfl_xor(v1, dist);
            const float ov2 = __shfl_xor(v2, dist);
            const int   oi1 = __shfl_xor(i1, dist);
            const int   oi2 = __shfl_xor(i2, dist);
            const int h = (q >> s) & 1;
            float a1, a2, bb1, bb2; int ai1, ai2, bj1, bj2;
            if (h) { a1 = ov1; a2 = ov2; ai1 = oi1; ai2 = oi2; bb1 = v1;  bb2 = v2;  bj1 = i1;  bj2 = i2; }
            else   { a1 = v1;  a2 = v2;  ai1 = i1;  ai2 = i2;  bb1 = ov1; bb2 = ov2; bj1 = oi1; bj2 = oi2; }
            if (bb1 > a1) {
                v1 = bb1; i1 = bj1;
                if (a1 >= bb2) { v2 = a1; i2 = ai1; } else { v2 = bb2; i2 = bj2; }
            } else {
                v1 = a1; i1 = ai1;
                if (bb1 > a2) { v2 = bb1; i2 = bj1; } else { v2 = a2; i2 = ai2; }
            }
        }
        if (q == 0) {
            const float ex = expf(v2 - v1);
            const float p1 = 1.f / (1.f + ex);
            TK[0 * BM + t] = p1;
            TK[1 * BM + t] = ex * p1;
            TK[2 * BM + t] = (float)i1;
            TK[3 * BM + t] = (float)i2;
        }
    }
    __syncthreads();

    // scattered writes (valid rows only)
    {
        const int t  = tid >> 3;
        const int c8 = (tid & 7) << 3;
        const int tok = LT[t];
        if (tok >= 0) {
            const float p1 = TK[t], p2 = TK[BM + t];
            const int i1 = (int)TK[2 * BM + t], i2 = (int)TK[3 * BM + t];
            float buf[8];
            #pragma unroll
            for (int jj = 0; jj < 8; ++jj) {
                const int e = c8 + jj;
                buf[jj] = (e == i1) ? p1 : (e == i2) ? p2 : 0.f;
            }
            float* dst = out_r + (size_t)tok * NEXP + c8;
            *(float4*)(dst + 0) = *(float4*)(buf + 0);
            *(float4*)(dst + 4) = *(float4*)(buf + 4);
        }
    }
    if (tid < BM && LT[tid] >= 0) {
        float2 v = make_float2(TK[2 * BM + tid], TK[3 * BM + tid]);
        *(float2*)(out_idx + (size_t)LT[tid] * 2) = v;
    }
}

// ---------- fallback: fused f32 kernel (insurance only) ----------
__global__ __launch_bounds__(256) void router_fused_f32(
    const float* __restrict__ x, const float* __restrict__ eps,
    const float* __restrict__ Wr, const float* __restrict__ br,
    const float* __restrict__ Wn, const float* __restrict__ bn,
    float* __restrict__ out_r, float* __restrict__ out_idx)
{
    __shared__ float xsm[32][64];
    __shared__ float ws2[32][128];
    __shared__ float lg[128][64];
    __shared__ float tk[4][64];
    const int tid = threadIdx.x;
    const int tx = tid & 15, ty = tid >> 4;
    const int m0 = blockIdx.x * 64;
    float acc[4][8];
    #pragma unroll
    for (int i = 0; i < 4; ++i)
        #pragma unroll
        for (int j = 0; j < 8; ++j) acc[i][j] = 0.f;
    for (int kc = 0; kc < NEMBD; kc += 32) {
        {
            const int tm = tid >> 2, kk = (tid & 3) << 3;
            const float* src = x + (size_t)(m0 + tm) * NEMBD + kc + kk;
            const float4 a = *(const float4*)(src);
            const float4 b = *(const float4*)(src + 4);
            xsm[kk+0][tm]=a.x; xsm[kk+1][tm]=a.y; xsm[kk+2][tm]=a.z; xsm[kk+3][tm]=a.w;
            xsm[kk+4][tm]=b.x; xsm[kk+5][tm]=b.y; xsm[kk+6][tm]=b.z; xsm[kk+7][tm]=b.w;
        }
        {
            const int kr = tid >> 3, q = tid & 7;
            const float* src = (q < 4)
                ? (Wr + (size_t)(kc + kr) * NEXP + (q << 4))
                : (Wn + (size_t)(kc + kr) * NEXP + ((q - 4) << 4));
            float* dst = &ws2[kr][q << 4];
            #pragma unroll
            for (int j = 0; j < 16; ++j) dst[j] = src[j];
        }
        __syncthreads();
        #pragma unroll
        for (int k = 0; k < 32; ++k) {
            const float4 xv = *(const float4*)&xsm[k][ty << 2];
            const float4 wa = *(const float4*)&ws2[k][tx << 3];
            const float4 wb = *(const float4*)&ws2[k][(tx << 3) + 4];
            const float xr[4] = {xv.x, xv.y, xv.z, xv.w};
            const float wcx[8] = {wa.x, wa.y, wa.z, wa.w, wb.x, wb.y, wb.z, wb.w};
            #pragma unroll
            for (int i = 0; i < 4; ++i)
                #pragma unroll
                for (int j = 0; j < 8; ++j)
                    acc[i][j] = fmaf(xr[i], wcx[j], acc[i][j]);
        }
        __syncthreads();
    }
    {
        const int n0 = tx << 3;
        #pragma unroll
        for (int j = 0; j < 8; ++j) {
            const int nn = n0 + j;
            const float b = (nn < NEXP) ? br[nn] : bn[nn - NEXP];
            #pragma unroll
            for (int i = 0; i < 4; ++i)
                lg[nn][(ty << 2) + i] = acc[i][j] + b;
        }
    }
    __syncthreads();
    if (tid < 64) {
        const int t = tid;
        const float* ep = eps + (size_t)(m0 + t) * NEXP;
        float v1 = -1e30f, v2 = -1e30f; int i1 = 0, i2 = 0;
        for (int e = 0; e < NEXP; ++e) {
            const float r = lg[e][t], nr = lg[NEXP + e][t];
            const float sp = fmaxf(nr, 0.f) + log1pf(expf(-fabsf(nr)));
            const float noisy = fmaf(ep[e], sp, r);
            if (noisy > v1) { v2=v1; i2=i1; v1=noisy; i1=e; }
            else if (noisy > v2) { v2=noisy; i2=e; }
        }
        const float ex = expf(v2 - v1);
        const float p1 = 1.f / (1.f + ex);
        tk[0][t]=p1; tk[1][t]=ex*p1; tk[2][t]=(float)i1; tk[3][t]=(float)i2;
    }
    __syncthreads();
    {
        const int t = tid >> 2, c = tid & 3;
        const float p1 = tk[0][t], p2 = tk[1][t];
        const int i1 = (int)tk[2][t], i2 = (int)tk[3][t];
        float buf[16];
        #pragma unroll
        for (int j = 0; j < 16; ++j) {
            const int e = (c << 4) + j;
            buf[j] = (e == i1) ? p1 : (e == i2) ? p2 : 0.f;
        }
        float* dst = out_r + (size_t)(m0 + t) * NEXP + (c << 4);
        *(float4*)(dst+0)=*(float4*)(buf+0); *(float4*)(dst+4)=*(float4*)(buf+4);
        *(float4*)(dst+8)=*(float4*)(buf+8); *(float4*)(dst+12)=*(float4*)(buf+12);
    }
    if (tid < 64) {
        float2 v = make_float2(tk[2][tid], tk[3][tid]);
        *(float2*)(out_idx + (size_t)(m0 + tid) * 2) = v;
    }
}

extern "C" void kernel_launch(void* const* d_in, const int* in_sizes, int n_in,
                              void* d_out, int out_size, void* d_ws, size_t ws_size,
                              hipStream_t stream) {
    const float* x  = (const float*)d_in[0];
    const float* ep = (const float*)d_in[1];
    const float* Wr = (const float*)d_in[2];
    const float* br = (const float*)d_in[3];
    const float* Wn = (const float*)d_in[4];
    const float* bn = (const float*)d_in[5];

    const int T = in_sizes[1] / NEXP;
    float* out_r   = (float*)d_out;
    float* out_idx = (float*)d_out + (size_t)T * NEXP;

    const size_t limb = (size_t)128 * NEMBD * sizeof(f16);     // 512 KB
    const size_t need = 2 * limb + 256 + (size_t)T * sizeof(int);
    if (ws_size >= need) {
        f16* wt_hi = (f16*)d_ws;
        f16* wt_lo = wt_hi + (size_t)128 * NEMBD;
        int* cnt   = (int*)((char*)d_ws + 2 * limb);
        int* list  = (int*)((char*)d_ws + 2 * limb + 256);

        hipMemsetAsync(cnt, 0, sizeof(int), stream);
        build_wt<<<64, 256, 0, stream>>>(Wr, Wn, wt_hi, wt_lo);
        router_fused9<<<T / BM, 512, 0, stream>>>(
            x, ep, wt_hi, br, bn, out_r, out_idx, cnt, list);
        router_fixup2<<<T / BM, 512, 0, stream>>>(
            x, ep, wt_hi, wt_lo, br, bn, out_r, out_idx, cnt, list);
    } else {
        router_fused_f32<<<T / 64, 256, 0, stream>>>(
            x, ep, Wr, br, Wn, bn, out_r, out_idx);
    }
}

// Round 13
// 101.984 us; speedup vs baseline: 1.5765x; 1.0312x over previous
//
#include <hip/hip_runtime.h>
#include <math.h>

// NoisyTopKRouter, round 13: round-12 structure with the graph-memset
// removed — cnt is zeroed by build_wt (block 0) instead of hipMemsetAsync,
// which showed up as a ~75us fillBufferAligned node per replay.
// Pipeline: build_wt -> router_fused9 (1-pass f16-hi canonical GEMM +
// top-3 gap certificate) -> router_fixup2 (gathered 3-limb exact mini-GEMM).

typedef _Float16 f16;
typedef _Float16 f16x8 __attribute__((ext_vector_type(8)));
typedef float    f32x4 __attribute__((ext_vector_type(4)));

#define NEMBD 2048
#define NEXP  64
#define BM    64
#define BK    64
#define ASTR  72              // XH row stride (f16)
#define LSTR  68              // LG col stride (f32)
#define WSCALE 64.0f
#define INV_WSCALE 0.015625f
#define TAU_C 2.2e-3f

union F4H8 { float4 f; f16x8 h; };

__device__ __forceinline__ f16x8 ld16h(const f16* p) {
    F4H8 u; u.f = *(const float4*)p; return u.h;
}

// ---------- kernel 0: W -> x64-scaled f16 limbs, [chunk][kgrp][col][8] ----------
__global__ __launch_bounds__(256) void build_wt(
    const float* __restrict__ Wr, const float* __restrict__ Wn,
    f16* __restrict__ wt_hi, f16* __restrict__ wt_lo,
    int* __restrict__ cnt)
{
    if (blockIdx.x == 0 && threadIdx.x == 0) *cnt = 0;   // replaces graph memset

    __shared__ float ws[32][129];
    const int c = blockIdx.x, t = threadIdx.x;
    const int k0 = c * 32;
    {
        const int k  = t >> 3;
        const int n8 = (t & 7) << 3;
        const float* s0 = Wr + (size_t)(k0 + k) * NEXP + n8;
        const float* s1 = Wn + (size_t)(k0 + k) * NEXP + n8;
        #pragma unroll
        for (int j = 0; j < 8; ++j) ws[k][n8 + j] = s0[j];
        #pragma unroll
        for (int j = 0; j < 8; ++j) ws[k][64 + n8 + j] = s1[j];
    }
    __syncthreads();
    {
        const int n  = t >> 1;           // col 0..127
        const int kh = (t & 1) << 4;     // k base 0 or 16
        const int kg = kh >> 3;          // kgrp 0 or 2
        f16x8 hv0, hv1, lv0, lv1;
        #pragma unroll
        for (int j = 0; j < 8; ++j) {
            const float v = ws[kh + j][n] * WSCALE;
            const f16 h = (f16)v;
            hv0[j] = h; lv0[j] = (f16)(v - (float)h);
        }
        #pragma unroll
        for (int j = 0; j < 8; ++j) {
            const float v = ws[kh + 8 + j][n] * WSCALE;
            const f16 h = (f16)v;
            hv1[j] = h; lv1[j] = (f16)(v - (float)h);
        }
        const size_t b0 = (size_t)c * 4096 + (size_t)kg * 1024 + n * 8;
        *(f16x8*)(wt_hi + b0)        = hv0;
        *(f16x8*)(wt_hi + b0 + 1024) = hv1;
        *(f16x8*)(wt_lo + b0)        = lv0;
        *(f16x8*)(wt_lo + b0 + 1024) = lv1;
    }
}

// ---------- kernel 1: canonical staged MFMA router (unchanged) ----------
__global__ __launch_bounds__(512, 2) void router_fused9(
    const float* __restrict__ x, const float* __restrict__ eps,
    const f16* __restrict__ wt_hi,
    const float* __restrict__ br, const float* __restrict__ bn,
    float* __restrict__ out_r, float* __restrict__ out_idx,
    int* __restrict__ cnt, int* __restrict__ list)
{
    __shared__ __align__(16) char SH[52224];
    f16* XH0 = (f16*)SH;
    f16* XH1 = XH0 + 64 * ASTR;
    f16* WH0 = (f16*)(SH + 18432);
    f16* WH1 = WH0 + 8192;
    float* LG = (float*)SH;
    float* TK = (float*)(SH + 51200);

    const int tid  = threadIdx.x;
    const int lane = tid & 63;
    const int w    = tid >> 6;
    const int wr   = w & 1;
    const int wc   = w >> 1;
    const int m0   = blockIdx.x * BM;

    const int row16 = lane & 15;
    const int kgrp  = lane >> 4;

    const int srow = tid >> 3;
    const int skof = (tid & 7) << 3;
    const float* axsrc = x + (size_t)(m0 + srow) * NEMBD + skof;
    const int axoff = srow * ASTR + skof;

    const f16* bsrc = wt_hi + tid * 16;

    const int aof0 = (wr * 32 + row16) * ASTR + kgrp * 8;
    const int aof1 = aof0 + 16 * ASTR;
    const int bof0 = kgrp * 1024 + (wc * 32 + row16) * 8;
    const int bof1 = bof0 + 16 * 8;

    f32x4 acc00 = {0.f,0.f,0.f,0.f}, acc01 = {0.f,0.f,0.f,0.f};
    f32x4 acc10 = {0.f,0.f,0.f,0.f}, acc11 = {0.f,0.f,0.f,0.f};

#define CVT8(A0, A1, hv) do { \
    hv[0] = (f16)A0.x; hv[1] = (f16)A0.y; hv[2] = (f16)A0.z; hv[3] = (f16)A0.w; \
    hv[4] = (f16)A1.x; hv[5] = (f16)A1.y; hv[6] = (f16)A1.z; hv[7] = (f16)A1.w; } while (0)

    {
        const float4 a0 = *(const float4*)(axsrc);
        const float4 a1 = *(const float4*)(axsrc + 4);
        F4H8 u0, u1;
        u0.f = *(const float4*)(bsrc);
        u1.f = *(const float4*)(bsrc + 8);
        f16x8 hv; CVT8(a0, a1, hv);
        *(f16x8*)(XH0 + axoff) = hv;
        *(f16x8*)(WH0 + tid * 16)     = u0.h;
        *(f16x8*)(WH0 + tid * 16 + 8) = u1.h;
        __syncthreads();
    }

#define STEP(XR, WR, XW, WW, s, doStage) do { \
    float4 a0_, a1_; F4H8 b0_, b1_; \
    if (doStage) { \
        a0_ = *(const float4*)(axsrc + (size_t)((s) + 1) * BK); \
        a1_ = *(const float4*)(axsrc + (size_t)((s) + 1) * BK + 4); \
        b0_.f = *(const float4*)(bsrc + (size_t)((s) + 1) * 8192); \
        b1_.f = *(const float4*)(bsrc + (size_t)((s) + 1) * 8192 + 8); \
        __builtin_amdgcn_sched_barrier(0); \
    } \
    _Pragma("unroll") \
    for (int ks = 0; ks < 2; ++ks) { \
        const f16x8 ah0 = *(const f16x8*)((XR) + aof0 + ks * 32); \
        const f16x8 ah1 = *(const f16x8*)((XR) + aof1 + ks * 32); \
        const f16x8 bh0 = *(const f16x8*)((WR) + ks * 4096 + bof0); \
        const f16x8 bh1 = *(const f16x8*)((WR) + ks * 4096 + bof1); \
        acc00 = __builtin_amdgcn_mfma_f32_16x16x32_f16(ah0, bh0, acc00, 0, 0, 0); \
        acc01 = __builtin_amdgcn_mfma_f32_16x16x32_f16(ah0, bh1, acc01, 0, 0, 0); \
        acc10 = __builtin_amdgcn_mfma_f32_16x16x32_f16(ah1, bh0, acc10, 0, 0, 0); \
        acc11 = __builtin_amdgcn_mfma_f32_16x16x32_f16(ah1, bh1, acc11, 0, 0, 0); \
    } \
    if (doStage) { \
        f16x8 hv_; CVT8(a0_, a1_, hv_); \
        *(f16x8*)((XW) + axoff) = hv_; \
        *(f16x8*)((WW) + tid * 16)     = b0_.h; \
        *(f16x8*)((WW) + tid * 16 + 8) = b1_.h; \
    } \
    __syncthreads(); \
} while (0)

    for (int s = 0; s < 32; s += 2) {
        STEP(XH0, WH0, XH1, WH1, s,     (s + 1) < 32);
        STEP(XH1, WH1, XH0, WH0, s + 1, (s + 2) < 32);
    }
#undef STEP

    {
        const int tokb = kgrp << 2;
        #pragma unroll
        for (int fj = 0; fj < 4; ++fj) {
            const int i = fj >> 1, j = fj & 1;
            const int col = wc * 32 + j * 16 + row16;
            const int tok = wr * 32 + i * 16 + tokb;
            const float bias = (col < NEXP) ? br[col] : bn[col - NEXP];
            const f32x4 a = (fj == 0) ? acc00 : (fj == 1) ? acc01 : (fj == 2) ? acc10 : acc11;
            #pragma unroll
            for (int r = 0; r < 4; ++r)
                LG[col * LSTR + tok + r] = a[r] * INV_WSCALE + bias;
        }
    }
    __syncthreads();

    if (tid < 256) {
        const int t = tid >> 2;
        const int q = tid & 3;
        const float* ep = eps + (size_t)(m0 + t) * NEXP;
        float v1 = -1e30f, v2 = -1e30f, v3 = -1e30f;
        int i1 = 0, i2 = 0, i3 = 0;
        float mx = 0.f;
        for (int j = 0; j < 16; ++j) {
            const int e = q * 16 + j;
            const float r  = LG[e * LSTR + t];
            const float nr = LG[(NEXP + e) * LSTR + t];
            const float sp = fmaxf(nr, 0.f) + log1pf(expf(-fabsf(nr)));
            const float ev = ep[e];
            mx = fmaxf(mx, fabsf(ev));
            const float noisy = fmaf(ev, sp, r);
            if (noisy > v1) { v3 = v2; i3 = i2; v2 = v1; i2 = i1; v1 = noisy; i1 = e; }
            else if (noisy > v2) { v3 = v2; i3 = i2; v2 = noisy; i2 = e; }
            else if (noisy > v3) { v3 = noisy; i3 = e; }
        }
        #pragma unroll
        for (int s = 0; s < 2; ++s) {
            const int dist = 1 << s;
            const float ov1 = __shfl_xor(v1, dist);
            const float ov2 = __shfl_xor(v2, dist);
            const float ov3 = __shfl_xor(v3, dist);
            const int   oi1 = __shfl_xor(i1, dist);
            const int   oi2 = __shfl_xor(i2, dist);
            const int   oi3 = __shfl_xor(i3, dist);
            mx = fmaxf(mx, __shfl_xor(mx, dist));
            const int h = (q >> s) & 1;
            float a1, a2, a3, bb1, bb2, bb3; int ai1, ai2, ai3, bj1, bj2, bj3;
            if (h) { a1=ov1;a2=ov2;a3=ov3;ai1=oi1;ai2=oi2;ai3=oi3;
                     bb1=v1;bb2=v2;bb3=v3;bj1=i1;bj2=i2;bj3=i3; }
            else   { a1=v1;a2=v2;a3=v3;ai1=i1;ai2=i2;ai3=i3;
                     bb1=ov1;bb2=ov2;bb3=ov3;bj1=oi1;bj2=oi2;bj3=oi3; }
            #pragma unroll
            for (int bi = 0; bi < 3; ++bi) {
                const float bv = (bi == 0) ? bb1 : (bi == 1) ? bb2 : bb3;
                const int   bj = (bi == 0) ? bj1 : (bi == 1) ? bj2 : bj3;
                if (bv > a1) { a3=a2;ai3=ai2; a2=a1;ai2=ai1; a1=bv;ai1=bj; }
                else if (bv > a2) { a3=a2;ai3=ai2; a2=bv;ai2=bj; }
                else if (bv > a3) { a3=bv;ai3=bj; }
            }
            v1=a1;v2=a2;v3=a3;i1=ai1;i2=ai2;i3=ai3;
        }
        if (q == 0) {
            const float e1 = fabsf(ep[i1]);
            const float e2 = fabsf(ep[i2]);
            const float em = fmaxf(e1, e2);
            const float t12 = TAU_C * sqrtf(2.f + e1 * e1 + e2 * e2);
            const float t23 = TAU_C * sqrtf(2.f + em * em + mx * mx);
            if ((v1 - v2 < t12) || (v2 - v3 < t23)) {
                const int ai = atomicAdd(cnt, 1);
                list[ai] = m0 + t;
            }
            const float ex = expf(v2 - v1);
            const float p1 = 1.f / (1.f + ex);
            TK[0 * BM + t] = p1;
            TK[1 * BM + t] = ex * p1;
            TK[2 * BM + t] = (float)i1;
            TK[3 * BM + t] = (float)i2;
        }
    }
    __syncthreads();

    {
        const int t  = tid >> 3;
        const int c8 = (tid & 7) << 3;
        const float p1 = TK[t], p2 = TK[BM + t];
        const int i1 = (int)TK[2 * BM + t], i2 = (int)TK[3 * BM + t];
        float buf[8];
        #pragma unroll
        for (int jj = 0; jj < 8; ++jj) {
            const int e = c8 + jj;
            buf[jj] = (e == i1) ? p1 : (e == i2) ? p2 : 0.f;
        }
        float* dst = out_r + (size_t)(m0 + t) * NEXP + c8;
        *(float4*)(dst + 0) = *(float4*)(buf + 0);
        *(float4*)(dst + 4) = *(float4*)(buf + 4);
    }
    if (tid < BM) {
        float2 v = make_float2(TK[2 * BM + tid], TK[3 * BM + tid]);
        *(float2*)(out_idx + (size_t)(m0 + tid) * 2) = v;
    }
}

// ---------- kernel 2: gathered mini-GEMM fixup (3-limb exact, unchanged) ----------
__global__ __launch_bounds__(512, 2) void router_fixup2(
    const float* __restrict__ x, const float* __restrict__ eps,
    const f16* __restrict__ wt_hi, const f16* __restrict__ wt_lo,
    const float* __restrict__ br, const float* __restrict__ bn,
    float* __restrict__ out_r, float* __restrict__ out_idx,
    const int* __restrict__ cnt, const int* __restrict__ list)
{
    __shared__ __align__(16) char SH[52480];
    f16* XH = (f16*)SH;
    f16* XL = XH + 64 * ASTR;
    f16* WH = (f16*)(SH + 18432);
    f16* WL = WH + 8192;
    float* LG = (float*)SH;
    float* TK = (float*)(SH + 51200);
    int*   LT = (int*)(SH + 52224);

    const int n  = cnt[0];
    const int m0 = blockIdx.x * BM;
    if (m0 >= n) return;

    const int tid  = threadIdx.x;
    const int lane = tid & 63;
    const int w    = tid >> 6;
    const int wr   = w & 1;
    const int wc   = w >> 1;

    if (tid < BM) LT[tid] = (m0 + tid < n) ? list[m0 + tid] : -1;
    __syncthreads();

    const int row16 = lane & 15;
    const int kgrp  = lane >> 4;

    const int srow = tid >> 3;
    const int skof = (tid & 7) << 3;
    const int tok_s = (LT[srow] >= 0) ? LT[srow] : LT[0];
    const float* axsrc = x + (size_t)tok_s * NEMBD + skof;
    const int axoff = srow * ASTR + skof;

    const f16* bsrc_h = wt_hi + tid * 16;
    const f16* bsrc_l = wt_lo + tid * 16;

    const int aof0 = (wr * 32 + row16) * ASTR + kgrp * 8;
    const int aof1 = aof0 + 16 * ASTR;
    const int bof0 = kgrp * 1024 + (wc * 32 + row16) * 8;
    const int bof1 = bof0 + 16 * 8;

    f32x4 acc00 = {0.f,0.f,0.f,0.f}, acc01 = {0.f,0.f,0.f,0.f};
    f32x4 acc10 = {0.f,0.f,0.f,0.f}, acc11 = {0.f,0.f,0.f,0.f};

    for (int s = 0; s < 32; ++s) {
        const float4 a0 = *(const float4*)(axsrc + (size_t)s * BK);
        const float4 a1 = *(const float4*)(axsrc + (size_t)s * BK + 4);
        F4H8 bh0_, bh1_, bl0_, bl1_;
        bh0_.f = *(const float4*)(bsrc_h + (size_t)s * 8192);
        bh1_.f = *(const float4*)(bsrc_h + (size_t)s * 8192 + 8);
        bl0_.f = *(const float4*)(bsrc_l + (size_t)s * 8192);
        bl1_.f = *(const float4*)(bsrc_l + (size_t)s * 8192 + 8);
        f16x8 hv, lv;
        {
            const float av[8] = {a0.x, a0.y, a0.z, a0.w, a1.x, a1.y, a1.z, a1.w};
            #pragma unroll
            for (int j = 0; j < 8; ++j) {
                const f16 h = (f16)av[j];
                hv[j] = h; lv[j] = (f16)(av[j] - (float)h);
            }
        }
        *(f16x8*)(XH + axoff) = hv;
        *(f16x8*)(XL + axoff) = lv;
        *(f16x8*)(WH + tid * 16)     = bh0_.h;
        *(f16x8*)(WH + tid * 16 + 8) = bh1_.h;
        *(f16x8*)(WL + tid * 16)     = bl0_.h;
        *(f16x8*)(WL + tid * 16 + 8) = bl1_.h;
        __syncthreads();
        #pragma unroll
        for (int ks = 0; ks < 2; ++ks) {
            const f16x8 ah0 = *(const f16x8*)(XH + aof0 + ks * 32);
            const f16x8 al0 = *(const f16x8*)(XL + aof0 + ks * 32);
            const f16x8 ah1 = *(const f16x8*)(XH + aof1 + ks * 32);
            const f16x8 al1 = *(const f16x8*)(XL + aof1 + ks * 32);
            const f16x8 bh0 = *(const f16x8*)(WH + ks * 4096 + bof0);
            const f16x8 bh1 = *(const f16x8*)(WH + ks * 4096 + bof1);
            const f16x8 bl0 = *(const f16x8*)(WL + ks * 4096 + bof0);
            const f16x8 bl1 = *(const f16x8*)(WL + ks * 4096 + bof1);
            acc00 = __builtin_amdgcn_mfma_f32_16x16x32_f16(ah0, bh0, acc00, 0, 0, 0);
            acc00 = __builtin_amdgcn_mfma_f32_16x16x32_f16(al0, bh0, acc00, 0, 0, 0);
            acc00 = __builtin_amdgcn_mfma_f32_16x16x32_f16(ah0, bl0, acc00, 0, 0, 0);
            acc01 = __builtin_amdgcn_mfma_f32_16x16x32_f16(ah0, bh1, acc01, 0, 0, 0);
            acc01 = __builtin_amdgcn_mfma_f32_16x16x32_f16(al0, bh1, acc01, 0, 0, 0);
            acc01 = __builtin_amdgcn_mfma_f32_16x16x32_f16(ah0, bl1, acc01, 0, 0, 0);
            acc10 = __builtin_amdgcn_mfma_f32_16x16x32_f16(ah1, bh0, acc10, 0, 0, 0);
            acc10 = __builtin_amdgcn_mfma_f32_16x16x32_f16(al1, bh0, acc10, 0, 0, 0);
            acc10 = __builtin_amdgcn_mfma_f32_16x16x32_f16(ah1, bl0, acc10, 0, 0, 0);
            acc11 = __builtin_amdgcn_mfma_f32_16x16x32_f16(ah1, bh1, acc11, 0, 0, 0);
            acc11 = __builtin_amdgcn_mfma_f32_16x16x32_f16(al1, bh1, acc11, 0, 0, 0);
            acc11 = __builtin_amdgcn_mfma_f32_16x16x32_f16(ah1, bl1, acc11, 0, 0, 0);
        }
        __syncthreads();
    }

    {
        const int tokb = kgrp << 2;
        #pragma unroll
        for (int fj = 0; fj < 4; ++fj) {
            const int i = fj >> 1, j = fj & 1;
            const int col = wc * 32 + j * 16 + row16;
            const int tok = wr * 32 + i * 16 + tokb;
            const float bias = (col < NEXP) ? br[col] : bn[col - NEXP];
            const f32x4 a = (fj == 0) ? acc00 : (fj == 1) ? acc01 : (fj == 2) ? acc10 : acc11;
            #pragma unroll
            for (int r = 0; r < 4; ++r)
                LG[col * LSTR + tok + r] = a[r] * INV_WSCALE + bias;
        }
    }
    __syncthreads();

    if (tid < 256) {
        const int t = tid >> 2;
        const int q = tid & 3;
        const int tok = LT[t];
        const float* ep = eps + (size_t)(tok >= 0 ? tok : LT[0]) * NEXP;
        float v1 = -1e30f, v2 = -1e30f;
        int i1 = 0, i2 = 0;
        for (int j = 0; j < 16; ++j) {
            const int e = q * 16 + j;
            const float r  = LG[e * LSTR + t];
            const float nr = LG[(NEXP + e) * LSTR + t];
            const float sp = fmaxf(nr, 0.f) + log1pf(expf(-fabsf(nr)));
            const float noisy = fmaf(ep[e], sp, r);
            if (noisy > v1) { v2 = v1; i2 = i1; v1 = noisy; i1 = e; }
            else if (noisy > v2) { v2 = noisy; i2 = e; }
        }
        #pragma unroll
        for (int s = 0; s < 2; ++s) {
            const int dist = 1 << s;
            const float ov1 = __shfl_xor(v1, dist);
            const float ov2 = __shfl_xor(v2, dist);
            const int   oi1 = __shfl_xor(i1, dist);
            const int   oi2 = __shfl_xor(i2, dist);
            const int h = (q >> s) & 1;
            float a1, a2, bb1, bb2; int ai1, ai2, bj1, bj2;
            if (h) { a1 = ov1; a2 = ov2; ai1 = oi1; ai2 = oi2; bb1 = v1;  bb2 = v2;  bj1 = i1;  bj2 = i2; }
            else   { a1 = v1;  a2 = v2;  ai1 = i1;  ai2 = i2;  bb1 = ov1; bb2 = ov2; bj1 = oi1; bj2 = oi2; }
            if (bb1 > a1) {
                v1 = bb1; i1 = bj1;
                if (a1 >= bb2) { v2 = a1; i2 = ai1; } else { v2 = bb2; i2 = bj2; }
            } else {
                v1 = a1; i1 = ai1;
                if (bb1 > a2) { v2 = bb1; i2 = bj1; } else { v2 = a2; i2 = ai2; }
            }
        }
        if (q == 0) {
            const float ex = expf(v2 - v1);
            const float p1 = 1.f / (1.f + ex);
            TK[0 * BM + t] = p1;
            TK[1 * BM + t] = ex * p1;
            TK[2 * BM + t] = (float)i1;
            TK[3 * BM + t] = (float)i2;
        }
    }
    __syncthreads();

    {
        const int t  = tid >> 3;
        const int c8 = (tid & 7) << 3;
        const int tok = LT[t];
        if (tok >= 0) {
            const float p1 = TK[t], p2 = TK[BM + t];
            const int i1 = (int)TK[2 * BM + t], i2 = (int)TK[3 * BM + t];
            float buf[8];
            #pragma unroll
            for (int jj = 0; jj < 8; ++jj) {
                const int e = c8 + jj;
                buf[jj] = (e == i1) ? p1 : (e == i2) ? p2 : 0.f;
            }
            float* dst = out_r + (size_t)tok * NEXP + c8;
            *(float4*)(dst + 0) = *(float4*)(buf + 0);
            *(float4*)(dst + 4) = *(float4*)(buf + 4);
        }
    }
    if (tid < BM && LT[tid] >= 0) {
        float2 v = make_float2(TK[2 * BM + tid], TK[3 * BM + tid]);
        *(float2*)(out_idx + (size_t)LT[tid] * 2) = v;
    }
}

// ---------- fallback: fused f32 kernel (insurance only) ----------
__global__ __launch_bounds__(256) void router_fused_f32(
    const float* __restrict__ x, const float* __restrict__ eps,
    const float* __restrict__ Wr, const float* __restrict__ br,
    const float* __restrict__ Wn, const float* __restrict__ bn,
    float* __restrict__ out_r, float* __restrict__ out_idx)
{
    __shared__ float xsm[32][64];
    __shared__ float ws2[32][128];
    __shared__ float lg[128][64];
    __shared__ float tk[4][64];
    const int tid = threadIdx.x;
    const int tx = tid & 15, ty = tid >> 4;
    const int m0 = blockIdx.x * 64;
    float acc[4][8];
    #pragma unroll
    for (int i = 0; i < 4; ++i)
        #pragma unroll
        for (int j = 0; j < 8; ++j) acc[i][j] = 0.f;
    for (int kc = 0; kc < NEMBD; kc += 32) {
        {
            const int tm = tid >> 2, kk = (tid & 3) << 3;
            const float* src = x + (size_t)(m0 + tm) * NEMBD + kc + kk;
            const float4 a = *(const float4*)(src);
            const float4 b = *(const float4*)(src + 4);
            xsm[kk+0][tm]=a.x; xsm[kk+1][tm]=a.y; xsm[kk+2][tm]=a.z; xsm[kk+3][tm]=a.w;
            xsm[kk+4][tm]=b.x; xsm[kk+5][tm]=b.y; xsm[kk+6][tm]=b.z; xsm[kk+7][tm]=b.w;
        }
        {
            const int kr = tid >> 3, q = tid & 7;
            const float* src = (q < 4)
                ? (Wr + (size_t)(kc + kr) * NEXP + (q << 4))
                : (Wn + (size_t)(kc + kr) * NEXP + ((q - 4) << 4));
            float* dst = &ws2[kr][q << 4];
            #pragma unroll
            for (int j = 0; j < 16; ++j) dst[j] = src[j];
        }
        __syncthreads();
        #pragma unroll
        for (int k = 0; k < 32; ++k) {
            const float4 xv = *(const float4*)&xsm[k][ty << 2];
            const float4 wa = *(const float4*)&ws2[k][tx << 3];
            const float4 wb = *(const float4*)&ws2[k][(tx << 3) + 4];
            const float xr[4] = {xv.x, xv.y, xv.z, xv.w};
            const float wcx[8] = {wa.x, wa.y, wa.z, wa.w, wb.x, wb.y, wb.z, wb.w};
            #pragma unroll
            for (int i = 0; i < 4; ++i)
                #pragma unroll
                for (int j = 0; j < 8; ++j)
                    acc[i][j] = fmaf(xr[i], wcx[j], acc[i][j]);
        }
        __syncthreads();
    }
    {
        const int n0 = tx << 3;
        #pragma unroll
        for (int j = 0; j < 8; ++j) {
            const int nn = n0 + j;
            const float b = (nn < NEXP) ? br[nn] : bn[nn - NEXP];
            #pragma unroll
            for (int i = 0; i < 4; ++i)
                lg[nn][(ty << 2) + i] = acc[i][j] + b;
        }
    }
    __syncthreads();
    if (tid < 64) {
        const int t = tid;
        const float* ep = eps + (size_t)(m0 + t) * NEXP;
        float v1 = -1e30f, v2 = -1e30f; int i1 = 0, i2 = 0;
        for (int e = 0; e < NEXP; ++e) {
            const float r = lg[e][t], nr = lg[NEXP + e][t];
            const float sp = fmaxf(nr, 0.f) + log1pf(expf(-fabsf(nr)));
            const float noisy = fmaf(ep[e], sp, r);
            if (noisy > v1) { v2=v1; i2=i1; v1=noisy; i1=e; }
            else if (noisy > v2) { v2=noisy; i2=e; }
        }
        const float ex = expf(v2 - v1);
        const float p1 = 1.f / (1.f + ex);
        tk[0][t]=p1; tk[1][t]=ex*p1; tk[2][t]=(float)i1; tk[3][t]=(float)i2;
    }
    __syncthreads();
    {
        const int t = tid >> 2, c = tid & 3;
        const float p1 = tk[0][t], p2 = tk[1][t];
        const int i1 = (int)tk[2][t], i2 = (int)tk[3][t];
        float buf[16];
        #pragma unroll
        for (int j = 0; j < 16; ++j) {
            const int e = (c << 4) + j;
            buf[j] = (e == i1) ? p1 : (e == i2) ? p2 : 0.f;
        }
        float* dst = out_r + (size_t)(m0 + t) * NEXP + (c << 4);
        *(float4*)(dst+0)=*(float4*)(buf+0); *(float4*)(dst+4)=*(float4*)(buf+4);
        *(float4*)(dst+8)=*(float4*)(buf+8); *(float4*)(dst+12)=*(float4*)(buf+12);
    }
    if (tid < 64) {
        float2 v = make_float2(tk[2][tid], tk[3][tid]);
        *(float2*)(out_idx + (size_t)(m0 + tid) * 2) = v;
    }
}

extern "C" void kernel_launch(void* const* d_in, const int* in_sizes, int n_in,
                              void* d_out, int out_size, void* d_ws, size_t ws_size,
                              hipStream_t stream) {
    const float* x  = (const float*)d_in[0];
    const float* ep = (const float*)d_in[1];
    const float* Wr = (const float*)d_in[2];
    const float* br = (const float*)d_in[3];
    const float* Wn = (const float*)d_in[4];
    const float* bn = (const float*)d_in[5];

    const int T = in_sizes[1] / NEXP;
    float* out_r   = (float*)d_out;
    float* out_idx = (float*)d_out + (size_t)T * NEXP;

    const size_t limb = (size_t)128 * NEMBD * sizeof(f16);     // 512 KB
    const size_t need = 2 * limb + 256 + (size_t)T * sizeof(int);
    if (ws_size >= need) {
        f16* wt_hi = (f16*)d_ws;
        f16* wt_lo = wt_hi + (size_t)128 * NEMBD;
        int* cnt   = (int*)((char*)d_ws + 2 * limb);
        int* list  = (int*)((char*)d_ws + 2 * limb + 256);

        build_wt<<<64, 256, 0, stream>>>(Wr, Wn, wt_hi, wt_lo, cnt);
        router_fused9<<<T / BM, 512, 0, stream>>>(
            x, ep, wt_hi, br, bn, out_r, out_idx, cnt, list);
        router_fixup2<<<T / BM, 512, 0, stream>>>(
            x, ep, wt_hi, wt_lo, br, bn, out_r, out_idx, cnt, list);
    } else {
        router_fused_f32<<<T / 64, 256, 0, stream>>>(
            x, ep, Wr, br, Wn, bn, out_r, out_idx);
    }
}